// Round 6
// baseline (1373.990 us; speedup 1.0000x reference)
//
#include <hip/hip_runtime.h>
#include <stdint.h>

#define D_MODEL 2048
#define NHEAD   16
#define DHEAD   128
#define BATCH   4
#define SEQ     2048
#define MROWS   (BATCH*SEQ)          // 8192
#define WELEMS  (D_MODEL*D_MODEL)    // 4194304

typedef __attribute__((ext_vector_type(4))) float          f32x4;
typedef __attribute__((ext_vector_type(8))) short          s16x8;
typedef __attribute__((ext_vector_type(4))) unsigned short u16x4;

// ---------- helpers ----------
__device__ __forceinline__ unsigned short f2bf(float f) {
  union { float f; uint32_t u; } v; v.f = f;
  uint32_t r = v.u + 0x7fffu + ((v.u >> 16) & 1u);   // RNE
  return (unsigned short)(r >> 16);
}

__device__ __forceinline__ void load_lds16(const void* g, void* l) {
  // LDS dest is wave-uniform base + lane*16 (HW semantics); global src per-lane.
  __builtin_amdgcn_global_load_lds(
      (__attribute__((address_space(1))) void*)(g),
      (__attribute__((address_space(3))) void*)(l), 16, 0, 0);
}

__device__ __forceinline__ float gamma_of(const double* sums, int gidx) {
  double gs = sums[gidx] * (1.0 / (double)WELEMS);
  if (gs < 1e-5) gs = 1e-5;
  return (float)gs;
}

// ---------- abs-mean reduction (fp64 accumulate, 4 weights) ----------
__global__ __launch_bounds__(256) void absmean_kernel(
    const float* __restrict__ w0, const float* __restrict__ w1,
    const float* __restrict__ w2, const float* __restrict__ w3,
    double* __restrict__ sums) {
  const float* w = blockIdx.y == 0 ? w0 : blockIdx.y == 1 ? w1
                 : blockIdx.y == 2 ? w2 : w3;
  double acc = 0.0;
  const int stride = gridDim.x * blockDim.x;
  for (int i = blockIdx.x * blockDim.x + threadIdx.x; i < WELEMS / 4; i += stride) {
    float4 v = ((const float4*)w)[i];
    acc += (double)fabsf(v.x) + (double)fabsf(v.y) +
           (double)fabsf(v.z) + (double)fabsf(v.w);
  }
  acc += __shfl_xor(acc, 1);  acc += __shfl_xor(acc, 2);  acc += __shfl_xor(acc, 4);
  acc += __shfl_xor(acc, 8);  acc += __shfl_xor(acc, 16); acc += __shfl_xor(acc, 32);
  __shared__ double wsum[4];
  const int lane = threadIdx.x & 63, wave = threadIdx.x >> 6;
  if (lane == 0) wsum[wave] = acc;
  __syncthreads();
  if (threadIdx.x == 0)
    atomicAdd(&sums[blockIdx.y], wsum[0] + wsum[1] + wsum[2] + wsum[3]);
}

// ---------- ternary quantize -> bf16 bits ----------
__global__ __launch_bounds__(256) void quant_kernel(
    const float* __restrict__ wsrc, unsigned short* __restrict__ wt,
    const double* __restrict__ sums, int gidx) {
  const float gf = gamma_of(sums, gidx);
  const int i = blockIdx.x * 256 + threadIdx.x;
  float4 v = ((const float4*)wsrc)[i];
  u16x4 r;
  r[0] = f2bf(fminf(1.f, fmaxf(-1.f, rintf(v.x / gf))));
  r[1] = f2bf(fminf(1.f, fmaxf(-1.f, rintf(v.y / gf))));
  r[2] = f2bf(fminf(1.f, fmaxf(-1.f, rintf(v.z / gf))));
  r[3] = f2bf(fminf(1.f, fmaxf(-1.f, rintf(v.w / gf))));
  ((u16x4*)wt)[i] = r;
}

// ---------- f32 -> bf16 convert ----------
__global__ __launch_bounds__(256) void cvt_bf16_kernel(
    const float* __restrict__ x, unsigned short* __restrict__ xb) {
  const int i = blockIdx.x * 256 + threadIdx.x;
  float4 v = ((const float4*)x)[i];
  u16x4 r;
  r[0] = f2bf(v.x); r[1] = f2bf(v.y); r[2] = f2bf(v.z); r[3] = f2bf(v.w);
  ((u16x4*)xb)[i] = r;
}

// ---------- GEMM: C = (A @ Bt^T) * gamma * escale  (m97 structure: 128x128, BK=32) ----------
// MODE 0: bf16 out (row,col). MODE 1: bf16 out transposed to (b,h,d,t). MODE 2: f32 out.
template <int MODE>
__global__ __launch_bounds__(256) void gemm_bt_kernel(
    const unsigned short* __restrict__ A,
    const unsigned short* __restrict__ Bt,
    void* __restrict__ out,
    const double* __restrict__ sums, int gidx, float escale) {
  constexpr int K = D_MODEL;
  __shared__ unsigned short As[128 * 32];   // [row][32k] 64B rows, linear
  __shared__ unsigned short Bs[128 * 32];
  const int tid = threadIdx.x, lane = tid & 63, wave = tid >> 6;
  const int g = lane >> 4, r15 = lane & 15;
  const int wm = wave >> 1, wn = wave & 1;
  const int rowBase = blockIdx.y * 128, colBase = blockIdx.x * 128;

  f32x4 acc[4][4] = {};

  const int o0 = wave * 1024 + lane * 16;
  const int o1 = 4096 + wave * 1024 + lane * 16;
  const unsigned short* Ap0 = A  + (size_t)(rowBase + (o0 >> 6)) * K + ((o0 >> 4) & 3) * 8;
  const unsigned short* Ap1 = A  + (size_t)(rowBase + (o1 >> 6)) * K + ((o1 >> 4) & 3) * 8;
  const unsigned short* Bp0 = Bt + (size_t)(colBase + (o0 >> 6)) * K + ((o0 >> 4) & 3) * 8;
  const unsigned short* Bp1 = Bt + (size_t)(colBase + (o1 >> 6)) * K + ((o1 >> 4) & 3) * 8;
  char* AsB = (char*)As; char* BsB = (char*)Bs;

  for (int kt = 0; kt < K; kt += 32) {
    load_lds16(Ap0 + kt, AsB + wave * 1024);
    load_lds16(Ap1 + kt, AsB + 4096 + wave * 1024);
    load_lds16(Bp0 + kt, BsB + wave * 1024);
    load_lds16(Bp1 + kt, BsB + 4096 + wave * 1024);
    __syncthreads();
    s16x8 a[4], b[4];
#pragma unroll
    for (int m = 0; m < 4; ++m)
      a[m] = *(const s16x8*)(AsB + (wm * 64 + m * 16 + r15) * 64 + g * 16);
#pragma unroll
    for (int n = 0; n < 4; ++n)
      b[n] = *(const s16x8*)(BsB + (wn * 64 + n * 16 + r15) * 64 + g * 16);
#pragma unroll
    for (int m = 0; m < 4; ++m)
#pragma unroll
      for (int n = 0; n < 4; ++n)
        acc[m][n] = __builtin_amdgcn_mfma_f32_16x16x32_bf16(a[m], b[n], acc[m][n], 0, 0, 0);
    __syncthreads();
  }

  const float scale = gamma_of(sums, gidx) * escale;
#pragma unroll
  for (int m = 0; m < 4; ++m) {
    const int row0 = rowBase + wm * 64 + m * 16 + g * 4;   // C/D: row=(l>>4)*4+j
#pragma unroll
    for (int n = 0; n < 4; ++n) {
      const int col = colBase + wn * 64 + n * 16 + r15;    // C/D: col=l&15
      if constexpr (MODE == 2) {
        float* op = (float*)out;
#pragma unroll
        for (int j = 0; j < 4; ++j)
          op[(size_t)(row0 + j) * D_MODEL + col] = acc[m][n][j] * scale;
      } else if constexpr (MODE == 0) {
        unsigned short* op = (unsigned short*)out;
#pragma unroll
        for (int j = 0; j < 4; ++j)
          op[(size_t)(row0 + j) * D_MODEL + col] = f2bf(acc[m][n][j] * scale);
      } else {  // MODE 1: write V^T laid out (b, h, d, t); 4 j's are contiguous t
        unsigned short* op = (unsigned short*)out;
        const int bb = row0 >> 11, t = row0 & 2047;
        const int hh = col >> 7,  d = col & 127;
        u16x4 r;
#pragma unroll
        for (int j = 0; j < 4; ++j) r[j] = f2bf(acc[m][n][j] * scale);
        *(u16x4*)(op + (((size_t)bb * NHEAD + hh) * DHEAD + d) * SEQ + t) = r;
      }
    }
  }
}

// ---------- causal flash attention ----------
// q: (B*T,2048) bf16 pre-scaled by gamma_q/sqrt(128)*log2(e). k: (B*T,2048) bf16 (gamma_k folded).
// vt: (B,H,128,T) bf16. out: (B*T,2048) bf16.
// Block = (b, h, PAIR of q-strips {qt, 15-qt}) -> uniform 36 staged tiles/block (load balance).
// 8 waves x 16 q-rows per strip. K double-buffered in LDS (XOR-swizzled, rule #21);
// V^T read DIRECTLY from global (L2-served; m169: V-staging that cache-fits is pure overhead).
// Dynamic LDS: Ks[2][64*128] (32KB) | Ps[8][16*64] (16KB) = 48KB -> 3 blocks/CU.
__global__ __launch_bounds__(512, 6) void attn_kernel(
    const unsigned short* __restrict__ qg,
    const unsigned short* __restrict__ kg,
    const unsigned short* __restrict__ vtg,
    unsigned short* __restrict__ og) {
  extern __shared__ char smem[];
  char* KsB = smem;                            // 2 x 16384 B
  const int tid = threadIdx.x, lane = tid & 63, wave = tid >> 6;
  const int g = lane >> 4, r15 = lane & 15;
  const int h = blockIdx.y, b = blockIdx.z;
  char* PsB = smem + 32768 + wave * 2048;      // per-wave [q16][kv64] 128B rows

  const unsigned short* kbase = kg + (size_t)b * SEQ * D_MODEL + h * DHEAD;
  const unsigned short* vbase = vtg + (size_t)(b * NHEAD + h) * DHEAD * SEQ;

  // stage K tile t into buffer buf (512 threads x 2 issues x 16B = 16KB)
  auto stageK = [&](int t, int buf) {
#pragma unroll
    for (int i = 0; i < 2; ++i) {
      const int ob = i * 8192 + wave * 1024 + lane * 16;
      const int krow = ob >> 8;
      const int ks = (ob & 255) ^ ((krow & 7) << 4);
      load_lds16(kbase + (size_t)(t * 64 + krow) * D_MODEL + (ks >> 1),
                 KsB + buf * 16384 + i * 8192 + wave * 1024);
    }
  };

#pragma unroll 1
  for (int si = 0; si < 2; ++si) {
    const int qt = si == 0 ? (int)blockIdx.x : 15 - (int)blockIdx.x;

    // Q fragments (A-layout: row=l&15, k=(l>>4)*8), hoisted for the strip
    s16x8 qf[4];
    {
      const unsigned short* qbase =
          qg + (size_t)(b * SEQ + qt * 128 + wave * 16 + r15) * D_MODEL + h * DHEAD;
#pragma unroll
      for (int c = 0; c < 4; ++c) qf[c] = *(const s16x8*)(qbase + c * 32 + g * 8);
    }

    f32x4 oacc[8] = {};
    float mr[4], lr[4];
#pragma unroll
    for (int j = 0; j < 4; ++j) { mr[j] = -1e30f; lr[j] = 0.f; }

    const int nt = 2 * qt + 2;                   // KV tiles for this strip
    const int qminw = qt * 128 + wave * 16;      // wave's lowest q row
    const int qmaxw = qminw + 15;

    stageK(0, 0);
    __syncthreads();                             // tile 0 ready
    int cur = 0;

    for (int t = 0; t < nt; ++t) {
      if (t + 1 < nt) stageK(t + 1, cur ^ 1);    // prefetch overlaps compute below

      if (t * 64 <= qmaxw) {                     // wave-uniform causal skip
        const bool maskedW = (t * 64 + 63 > qminw);
        const char* Kb = KsB + cur * 16384;

        // ---- S = Q K^T  (16 q-rows x 64 keys, log2 units: scale folded into Q)
        f32x4 s[4] = {};
        __builtin_amdgcn_s_setprio(1);
#pragma unroll
        for (int c = 0; c < 4; ++c) {
#pragma unroll
          for (int n = 0; n < 4; ++n) {
            const int key = n * 16 + r15;
            const int baddr = (((key << 8) | (c << 6) | (g << 4))) ^ ((key & 7) << 4);
            s16x8 kf = *(const s16x8*)(Kb + baddr);
            s[n] = __builtin_amdgcn_mfma_f32_16x16x32_bf16(qf[c], kf, s[n], 0, 0, 0);
          }
        }
        __builtin_amdgcn_s_setprio(0);
        if (maskedW) {
          const int q0 = qminw + g * 4;
          const int k0 = t * 64 + r15;
#pragma unroll
          for (int n = 0; n < 4; ++n)
#pragma unroll
            for (int j = 0; j < 4; ++j)
              if (k0 + n * 16 > q0 + j) s[n][j] = -1e30f;
        }
        float pm[4];
#pragma unroll
        for (int j = 0; j < 4; ++j)
          pm[j] = fmaxf(fmaxf(s[0][j], s[1][j]), fmaxf(s[2][j], s[3][j]));
#pragma unroll
        for (int j = 0; j < 4; ++j) {
          pm[j] = fmaxf(pm[j], __shfl_xor(pm[j], 1));
          pm[j] = fmaxf(pm[j], __shfl_xor(pm[j], 2));
          pm[j] = fmaxf(pm[j], __shfl_xor(pm[j], 4));
          pm[j] = fmaxf(pm[j], __shfl_xor(pm[j], 8));
        }
        // defer-max (T13): skip rescale while max growth < 8 (log2 units, P <= 256)
        bool ok = pm[0] <= mr[0] + 8.f && pm[1] <= mr[1] + 8.f &&
                  pm[2] <= mr[2] + 8.f && pm[3] <= mr[3] + 8.f;
        if (!__all(ok)) {
#pragma unroll
          for (int j = 0; j < 4; ++j) {
            const float mn = fmaxf(mr[j], pm[j]);
            const float rf = exp2f(mr[j] - mn);
            mr[j] = mn;
            lr[j] *= rf;
#pragma unroll
            for (int n2 = 0; n2 < 8; ++n2) oacc[n2][j] *= rf;
          }
        }
        // ---- P = exp2(S-m): row-sum + bf16 P into swizzled per-wave LDS
        float psum[4] = {0.f, 0.f, 0.f, 0.f};
#pragma unroll
        for (int n = 0; n < 4; ++n) {
          const int keyl = n * 16 + r15;
#pragma unroll
          for (int j = 0; j < 4; ++j) {
            const float p = exp2f(s[n][j] - mr[j]);
            psum[j] += p;
            const int row = g * 4 + j;
            const int baddr = ((row << 7) | (keyl << 1)) ^ ((row & 7) << 4);
            *(unsigned short*)(PsB + baddr) = f2bf(p);
          }
        }
#pragma unroll
        for (int j = 0; j < 4; ++j) {
          psum[j] += __shfl_xor(psum[j], 1);
          psum[j] += __shfl_xor(psum[j], 2);
          psum[j] += __shfl_xor(psum[j], 4);
          psum[j] += __shfl_xor(psum[j], 8);
          lr[j] += psum[j];
        }
        // ---- O += P V: A = P from per-wave LDS; B = V^T rows read DIRECT from global.
        //      B-frag: col=d (lane&15 within 16-chunk), k=key=c2*32+g*8+i (8 consecutive t)
        __builtin_amdgcn_s_setprio(1);
#pragma unroll
        for (int c2 = 0; c2 < 2; ++c2) {
          const int baddr_p = (((r15 << 7) | (c2 << 6) | (g << 4))) ^ ((r15 & 7) << 4);
          s16x8 pa = *(const s16x8*)(PsB + baddr_p);
#pragma unroll
          for (int n2 = 0; n2 < 8; ++n2) {
            const int d = n2 * 16 + r15;
            s16x8 vf = *(const s16x8*)(vbase + (size_t)d * SEQ + t * 64 + c2 * 32 + g * 8);
            oacc[n2] = __builtin_amdgcn_mfma_f32_16x16x32_bf16(pa, vf, oacc[n2], 0, 0, 0);
          }
        }
        __builtin_amdgcn_s_setprio(0);
      }
      __syncthreads();   // drains vmcnt (K(t+1) staged) + guards K buffers
      cur ^= 1;
    }

    // ---- normalize + write (b,t,h,d)
    unsigned short* obase =
        og + (size_t)(b * SEQ + qt * 128 + wave * 16 + g * 4) * D_MODEL + h * DHEAD;
    float inv[4];
#pragma unroll
    for (int j = 0; j < 4; ++j) inv[j] = 1.f / lr[j];
#pragma unroll
    for (int n2 = 0; n2 < 8; ++n2) {
      const int d = n2 * 16 + r15;
#pragma unroll
      for (int j = 0; j < 4; ++j)
        obase[(size_t)j * D_MODEL + d] = f2bf(oacc[n2][j] * inv[j]);
    }
    __syncthreads();     // strip boundary: K/P buffers safe to reuse
  }
}

// ---------- launch ----------
extern "C" void kernel_launch(void* const* d_in, const int* in_sizes, int n_in,
                              void* d_out, int out_size, void* d_ws, size_t ws_size,
                              hipStream_t stream) {
  const float* x  = (const float*)d_in[0];
  const float* wq = (const float*)d_in[1];
  const float* wk = (const float*)d_in[2];
  const float* wv = (const float*)d_in[3];
  const float* wo = (const float*)d_in[4];
  float* out = (float*)d_out;

  char* ws = (char*)d_ws;
  double* sums = (double*)ws;
  size_t off = 256;
  unsigned short* wtern = (unsigned short*)(ws + off); off += (size_t)WELEMS * 2;
  unsigned short* xbf   = (unsigned short*)(ws + off); off += (size_t)MROWS * D_MODEL * 2;
  unsigned short* qb    = (unsigned short*)(ws + off); off += (size_t)MROWS * D_MODEL * 2;
  unsigned short* kb    = (unsigned short*)(ws + off); off += (size_t)MROWS * D_MODEL * 2;
  unsigned short* vtb   = (unsigned short*)(ws + off); off += (size_t)MROWS * D_MODEL * 2;
  unsigned short* attn_out = xbf;  // x no longer needed after the 3 QKV GEMMs

  hipMemsetAsync(sums, 0, 4 * sizeof(double), stream);
  absmean_kernel<<<dim3(256, 4), 256, 0, stream>>>(wq, wk, wv, wo, sums);
  cvt_bf16_kernel<<<MROWS * D_MODEL / 4 / 256, 256, 0, stream>>>(x, xbf);

  // Q carries 1/sqrt(128) * log2(e) so attention scores are in log2 units (exp2f native)
  const float qfold = 0.08838834764831845f * 1.4426950408889634f;

  const dim3 ggrid(D_MODEL / 128, MROWS / 128);
  quant_kernel<<<WELEMS / 4 / 256, 256, 0, stream>>>(wq, wtern, sums, 0);
  gemm_bt_kernel<0><<<ggrid, 256, 0, stream>>>(xbf, wtern, qb, sums, 0, qfold);
  quant_kernel<<<WELEMS / 4 / 256, 256, 0, stream>>>(wk, wtern, sums, 1);
  gemm_bt_kernel<0><<<ggrid, 256, 0, stream>>>(xbf, wtern, kb, sums, 1, 1.0f);
  quant_kernel<<<WELEMS / 4 / 256, 256, 0, stream>>>(wv, wtern, sums, 2);
  gemm_bt_kernel<1><<<ggrid, 256, 0, stream>>>(xbf, wtern, vtb, sums, 2, 1.0f);

  attn_kernel<<<dim3(8, NHEAD, BATCH), 512, 49152, stream>>>(qb, kb, vtb, attn_out);

  quant_kernel<<<WELEMS / 4 / 256, 256, 0, stream>>>(wo, wtern, sums, 3);
  gemm_bt_kernel<2><<<ggrid, 256, 0, stream>>>(attn_out, wtern, out, sums, 3, 1.0f);
}

// Round 9
// 988.483 us; speedup vs baseline: 1.3900x; 1.3900x over previous
//
#include <hip/hip_runtime.h>
#include <stdint.h>

#define D_MODEL 2048
#define NHEAD   16
#define DHEAD   128
#define BATCH   4
#define SEQ     2048
#define MROWS   (BATCH*SEQ)          // 8192
#define WELEMS  (D_MODEL*D_MODEL)    // 4194304

typedef __attribute__((ext_vector_type(4))) float          f32x4;
typedef __attribute__((ext_vector_type(8))) short          s16x8;
typedef __attribute__((ext_vector_type(4))) unsigned short u16x4;

// ---------- helpers ----------
__device__ __forceinline__ unsigned short f2bf(float f) {
  union { float f; uint32_t u; } v; v.f = f;
  uint32_t r = v.u + 0x7fffu + ((v.u >> 16) & 1u);   // RNE
  return (unsigned short)(r >> 16);
}

__device__ __forceinline__ void load_lds16(const void* g, void* l) {
  // LDS dest is wave-uniform base + lane*16 (HW semantics); global src per-lane.
  __builtin_amdgcn_global_load_lds(
      (__attribute__((address_space(1))) void*)(g),
      (__attribute__((address_space(3))) void*)(l), 16, 0, 0);
}

__device__ __forceinline__ float gamma_of(const double* sums, int gidx) {
  double gs = sums[gidx] * (1.0 / (double)WELEMS);
  if (gs < 1e-5) gs = 1e-5;
  return (float)gs;
}

// ---------- abs-mean reduction (fp64 accumulate, 4 weights) ----------
__global__ __launch_bounds__(256) void absmean_kernel(
    const float* __restrict__ w0, const float* __restrict__ w1,
    const float* __restrict__ w2, const float* __restrict__ w3,
    double* __restrict__ sums) {
  const float* w = blockIdx.y == 0 ? w0 : blockIdx.y == 1 ? w1
                 : blockIdx.y == 2 ? w2 : w3;
  double acc = 0.0;
  const int stride = gridDim.x * blockDim.x;
  for (int i = blockIdx.x * blockDim.x + threadIdx.x; i < WELEMS / 4; i += stride) {
    float4 v = ((const float4*)w)[i];
    acc += (double)fabsf(v.x) + (double)fabsf(v.y) +
           (double)fabsf(v.z) + (double)fabsf(v.w);
  }
  acc += __shfl_xor(acc, 1);  acc += __shfl_xor(acc, 2);  acc += __shfl_xor(acc, 4);
  acc += __shfl_xor(acc, 8);  acc += __shfl_xor(acc, 16); acc += __shfl_xor(acc, 32);
  __shared__ double wsum[4];
  const int lane = threadIdx.x & 63, wave = threadIdx.x >> 6;
  if (lane == 0) wsum[wave] = acc;
  __syncthreads();
  if (threadIdx.x == 0)
    atomicAdd(&sums[blockIdx.y], wsum[0] + wsum[1] + wsum[2] + wsum[3]);
}

// ---------- ternary quantize -> bf16 bits ----------
__global__ __launch_bounds__(256) void quant_kernel(
    const float* __restrict__ wsrc, unsigned short* __restrict__ wt,
    const double* __restrict__ sums, int gidx) {
  const float gf = gamma_of(sums, gidx);
  const int i = blockIdx.x * 256 + threadIdx.x;
  float4 v = ((const float4*)wsrc)[i];
  u16x4 r;
  r[0] = f2bf(fminf(1.f, fmaxf(-1.f, rintf(v.x / gf))));
  r[1] = f2bf(fminf(1.f, fmaxf(-1.f, rintf(v.y / gf))));
  r[2] = f2bf(fminf(1.f, fmaxf(-1.f, rintf(v.z / gf))));
  r[3] = f2bf(fminf(1.f, fmaxf(-1.f, rintf(v.w / gf))));
  ((u16x4*)wt)[i] = r;
}

// ---------- f32 -> bf16 convert ----------
__global__ __launch_bounds__(256) void cvt_bf16_kernel(
    const float* __restrict__ x, unsigned short* __restrict__ xb) {
  const int i = blockIdx.x * 256 + threadIdx.x;
  float4 v = ((const float4*)x)[i];
  u16x4 r;
  r[0] = f2bf(v.x); r[1] = f2bf(v.y); r[2] = f2bf(v.z); r[3] = f2bf(v.w);
  ((u16x4*)xb)[i] = r;
}

// ---------- GEMM: C = (A @ Bt^T) * gamma * escale  (m97 structure: 128x128, BK=32) ----------
// MODE 0: bf16 out (row,col). MODE 1: bf16 out transposed to (b,h,d,t). MODE 2: f32 out.
// Grid is FIXED at (16, 64); blockIdx is XCD-swizzled (T1, bijective since 1024 % 8 == 0).
template <int MODE>
__global__ __launch_bounds__(256) void gemm_bt_kernel(
    const unsigned short* __restrict__ A,
    const unsigned short* __restrict__ Bt,
    void* __restrict__ out,
    const double* __restrict__ sums, int gidx, float escale) {
  constexpr int K = D_MODEL;
  __shared__ unsigned short As[128 * 32];   // [row][32k] 64B rows, linear
  __shared__ unsigned short Bs[128 * 32];
  const int tid = threadIdx.x, lane = tid & 63, wave = tid >> 6;
  const int g = lane >> 4, r15 = lane & 15;
  const int wm = wave >> 1, wn = wave & 1;

  // XCD-aware swizzle: consecutive wg' within one XCD share A/B panels (L2 locality)
  const int lin = blockIdx.y * 16 + blockIdx.x;     // 0..1023
  const int wg  = (lin & 7) * 128 + (lin >> 3);     // bijective (1024 = 8*128)
  const int rowBase = (wg >> 4) * 128, colBase = (wg & 15) * 128;

  f32x4 acc[4][4] = {};

  const int o0 = wave * 1024 + lane * 16;
  const int o1 = 4096 + wave * 1024 + lane * 16;
  const unsigned short* Ap0 = A  + (size_t)(rowBase + (o0 >> 6)) * K + ((o0 >> 4) & 3) * 8;
  const unsigned short* Ap1 = A  + (size_t)(rowBase + (o1 >> 6)) * K + ((o1 >> 4) & 3) * 8;
  const unsigned short* Bp0 = Bt + (size_t)(colBase + (o0 >> 6)) * K + ((o0 >> 4) & 3) * 8;
  const unsigned short* Bp1 = Bt + (size_t)(colBase + (o1 >> 6)) * K + ((o1 >> 4) & 3) * 8;
  char* AsB = (char*)As; char* BsB = (char*)Bs;

  for (int kt = 0; kt < K; kt += 32) {
    load_lds16(Ap0 + kt, AsB + wave * 1024);
    load_lds16(Ap1 + kt, AsB + 4096 + wave * 1024);
    load_lds16(Bp0 + kt, BsB + wave * 1024);
    load_lds16(Bp1 + kt, BsB + 4096 + wave * 1024);
    __syncthreads();
    s16x8 a[4], b[4];
#pragma unroll
    for (int m = 0; m < 4; ++m)
      a[m] = *(const s16x8*)(AsB + (wm * 64 + m * 16 + r15) * 64 + g * 16);
#pragma unroll
    for (int n = 0; n < 4; ++n)
      b[n] = *(const s16x8*)(BsB + (wn * 64 + n * 16 + r15) * 64 + g * 16);
#pragma unroll
    for (int m = 0; m < 4; ++m)
#pragma unroll
      for (int n = 0; n < 4; ++n)
        acc[m][n] = __builtin_amdgcn_mfma_f32_16x16x32_bf16(a[m], b[n], acc[m][n], 0, 0, 0);
    __syncthreads();
  }

  const float scale = gamma_of(sums, gidx) * escale;
#pragma unroll
  for (int m = 0; m < 4; ++m) {
    const int row0 = rowBase + wm * 64 + m * 16 + g * 4;   // C/D: row=(l>>4)*4+j
#pragma unroll
    for (int n = 0; n < 4; ++n) {
      const int col = colBase + wn * 64 + n * 16 + r15;    // C/D: col=l&15
      if constexpr (MODE == 2) {
        float* op = (float*)out;
#pragma unroll
        for (int j = 0; j < 4; ++j)
          op[(size_t)(row0 + j) * D_MODEL + col] = acc[m][n][j] * scale;
      } else if constexpr (MODE == 0) {
        unsigned short* op = (unsigned short*)out;
#pragma unroll
        for (int j = 0; j < 4; ++j)
          op[(size_t)(row0 + j) * D_MODEL + col] = f2bf(acc[m][n][j] * scale);
      } else {  // MODE 1: write V^T laid out (b, h, d, t); 4 j's are contiguous t
        unsigned short* op = (unsigned short*)out;
        const int bb = row0 >> 11, t = row0 & 2047;
        const int hh = col >> 7,  d = col & 127;
        u16x4 r;
#pragma unroll
        for (int j = 0; j < 4; ++j) r[j] = f2bf(acc[m][n][j] * scale);
        *(u16x4*)(op + (((size_t)bb * NHEAD + hh) * DHEAD + d) * SEQ + t) = r;
      }
    }
  }
}

// ---------- causal flash attention ----------
// q: (B*T,2048) bf16 pre-scaled by gamma_q/sqrt(128)*log2(e). k: (B*T,2048) bf16 (gamma_k folded).
// vt: (B,H,128,T) bf16. out: (B*T,2048) bf16.
// R0 geometry (fastest measured): 256 threads = 4 waves x 16 q-rows, 64-row q-strips,
// K AND V staged in 40KB static LDS, 2 barriers/tile. NEW: each block processes a PAIR of
// strips {qt, 31-qt} -> uniform 33 staged tiles/block, grid 1024 blocks, 4 blocks/CU
// (40KB LDS, ~104 VGPR) -> ~16 waves/CU sustained (kills R0's ramp/tail imbalance).
// Scores in log2 units (exp2f); defer-max (T13); mask only the diagonal tile; setprio on MFMA.
// LDS tiles XOR-swizzled byte^=((row&7)<<4) via pre-swizzled global source (rule #21).
__global__ __launch_bounds__(256, 4) void attn_kernel(
    const unsigned short* __restrict__ qg,
    const unsigned short* __restrict__ kg,
    const unsigned short* __restrict__ vtg,
    unsigned short* __restrict__ og) {
  __shared__ unsigned short Ks[64 * 128];    // [key][d]  256B rows, 16KB
  __shared__ unsigned short Vts[128 * 64];   // [d][kv]   128B rows, 16KB
  __shared__ unsigned short Ps[4][1024];     // per-wave [q16][kv64] 128B rows, 8KB

  const int tid = threadIdx.x, lane = tid & 63, wave = tid >> 6;
  const int g = lane >> 4, r15 = lane & 15;
  const int h = blockIdx.y, b = blockIdx.z;

  char* KsB = (char*)Ks; char* VtsB = (char*)Vts; char* PsB = (char*)(Ps[wave]);
  const unsigned short* kbase = kg + (size_t)b * SEQ * D_MODEL + h * DHEAD;
  const unsigned short* vbase = vtg + (size_t)(b * NHEAD + h) * DHEAD * SEQ;

#pragma unroll 1
  for (int si = 0; si < 2; ++si) {
    const int qs = si == 0 ? (int)blockIdx.x : 31 - (int)blockIdx.x;  // 64-row strip index

    // Q fragments (A-layout: row=l&15, k=(l>>4)*8), hoisted for the strip
    s16x8 qf[4];
    {
      const unsigned short* qbase =
          qg + (size_t)(b * SEQ + qs * 64 + wave * 16 + r15) * D_MODEL + h * DHEAD;
#pragma unroll
      for (int c = 0; c < 4; ++c) qf[c] = *(const s16x8*)(qbase + c * 32 + g * 8);
    }

    f32x4 oacc[8] = {};
    float mr[4], lr[4];
#pragma unroll
    for (int j = 0; j < 4; ++j) { mr[j] = -1e30f; lr[j] = 0.f; }

    const int nt = qs + 1;                    // KV tiles for this strip

#pragma unroll 1
    for (int t = 0; t < nt; ++t) {
      // ---- stage K (16KB) and Vt (16KB): linear LDS, pre-swizzled global source
#pragma unroll
      for (int rnd = 0; rnd < 4; ++rnd) {
        const int ob = rnd * 4096 + wave * 1024 + lane * 16;
        const int krow = ob >> 8;
        const int ks = (ob & 255) ^ ((krow & 7) << 4);
        load_lds16(kbase + (size_t)(t * 64 + krow) * D_MODEL + (ks >> 1),
                   KsB + rnd * 4096 + wave * 1024);
        const int drow = ob >> 7;
        const int vs = (ob & 127) ^ ((drow & 7) << 4);
        load_lds16(vbase + (size_t)drow * SEQ + t * 64 + (vs >> 1),
                   VtsB + rnd * 4096 + wave * 1024);
      }
      __syncthreads();

      // ---- S = Q K^T  (16 q-rows x 64 keys, log2 units: scale folded into Q)
      f32x4 s[4] = {};
      __builtin_amdgcn_s_setprio(1);
#pragma unroll
      for (int c = 0; c < 4; ++c) {
#pragma unroll
        for (int n = 0; n < 4; ++n) {
          const int key = n * 16 + r15;
          const int baddr = (((key << 8) | (c << 6) | (g << 4))) ^ ((key & 7) << 4);
          s16x8 kf = *(const s16x8*)(KsB + baddr);
          s[n] = __builtin_amdgcn_mfma_f32_16x16x32_bf16(qf[c], kf, s[n], 0, 0, 0);
        }
      }
      __builtin_amdgcn_s_setprio(0);

      if (t == qs) {                          // only the diagonal tile needs the causal mask
        const int q0 = qs * 64 + wave * 16 + g * 4;
        const int k0 = t * 64 + r15;
#pragma unroll
        for (int n = 0; n < 4; ++n)
#pragma unroll
          for (int j = 0; j < 4; ++j)
            if (k0 + n * 16 > q0 + j) s[n][j] = -1e30f;
      }
      float pm[4];
#pragma unroll
      for (int j = 0; j < 4; ++j)
        pm[j] = fmaxf(fmaxf(s[0][j], s[1][j]), fmaxf(s[2][j], s[3][j]));
#pragma unroll
      for (int j = 0; j < 4; ++j) {
        pm[j] = fmaxf(pm[j], __shfl_xor(pm[j], 1));
        pm[j] = fmaxf(pm[j], __shfl_xor(pm[j], 2));
        pm[j] = fmaxf(pm[j], __shfl_xor(pm[j], 4));
        pm[j] = fmaxf(pm[j], __shfl_xor(pm[j], 8));
      }
      // defer-max (T13): skip rescale while max growth < 8 (log2 units, P <= 256)
      bool ok = pm[0] <= mr[0] + 8.f && pm[1] <= mr[1] + 8.f &&
                pm[2] <= mr[2] + 8.f && pm[3] <= mr[3] + 8.f;
      if (!__all(ok)) {
#pragma unroll
        for (int j = 0; j < 4; ++j) {
          const float mn = fmaxf(mr[j], pm[j]);
          const float rf = exp2f(mr[j] - mn);
          mr[j] = mn;
          lr[j] *= rf;
#pragma unroll
          for (int n2 = 0; n2 < 8; ++n2) oacc[n2][j] *= rf;
        }
      }
      // ---- P = exp2(S-m): row-sum + bf16 P into swizzled per-wave LDS
      float psum[4] = {0.f, 0.f, 0.f, 0.f};
#pragma unroll
      for (int n = 0; n < 4; ++n) {
        const int keyl = n * 16 + r15;
#pragma unroll
        for (int j = 0; j < 4; ++j) {
          const float p = exp2f(s[n][j] - mr[j]);
          psum[j] += p;
          const int row = g * 4 + j;
          const int baddr = ((row << 7) | (keyl << 1)) ^ ((row & 7) << 4);
          *(unsigned short*)(PsB + baddr) = f2bf(p);
        }
      }
#pragma unroll
      for (int j = 0; j < 4; ++j) {
        psum[j] += __shfl_xor(psum[j], 1);
        psum[j] += __shfl_xor(psum[j], 2);
        psum[j] += __shfl_xor(psum[j], 4);
        psum[j] += __shfl_xor(psum[j], 8);
        lr[j] += psum[j];
      }
      // ---- O += P V   (A = P from per-wave LDS, B = Vt rows; in-wave order is safe)
      __builtin_amdgcn_s_setprio(1);
#pragma unroll
      for (int c2 = 0; c2 < 2; ++c2) {
        const int baddr_p = (((r15 << 7) | (c2 << 6) | (g << 4))) ^ ((r15 & 7) << 4);
        s16x8 pa = *(const s16x8*)(PsB + baddr_p);
#pragma unroll
        for (int n2 = 0; n2 < 8; ++n2) {
          const int d = n2 * 16 + r15;
          const int baddr_v = (((d << 7) | (c2 << 6) | (g << 4))) ^ ((d & 7) << 4);
          s16x8 vf = *(const s16x8*)(VtsB + baddr_v);
          oacc[n2] = __builtin_amdgcn_mfma_f32_16x16x32_bf16(pa, vf, oacc[n2], 0, 0, 0);
        }
      }
      __builtin_amdgcn_s_setprio(0);
      __syncthreads();   // guard Ks/Vts before next tile's staging
    }

    // ---- normalize + write (b,t,h,d)
    unsigned short* obase =
        og + (size_t)(b * SEQ + qs * 64 + wave * 16 + g * 4) * D_MODEL + h * DHEAD;
    float inv[4];
#pragma unroll
    for (int j = 0; j < 4; ++j) inv[j] = 1.f / lr[j];
#pragma unroll
    for (int n2 = 0; n2 < 8; ++n2) {
      const int d = n2 * 16 + r15;
#pragma unroll
      for (int j = 0; j < 4; ++j)
        obase[(size_t)j * D_MODEL + d] = f2bf(oacc[n2][j] * inv[j]);
    }
  }
}

// ---------- launch ----------
extern "C" void kernel_launch(void* const* d_in, const int* in_sizes, int n_in,
                              void* d_out, int out_size, void* d_ws, size_t ws_size,
                              hipStream_t stream) {
  const float* x  = (const float*)d_in[0];
  const float* wq = (const float*)d_in[1];
  const float* wk = (const float*)d_in[2];
  const float* wv = (const float*)d_in[3];
  const float* wo = (const float*)d_in[4];
  float* out = (float*)d_out;

  char* ws = (char*)d_ws;
  double* sums = (double*)ws;
  size_t off = 256;
  unsigned short* wtern = (unsigned short*)(ws + off); off += (size_t)WELEMS * 2;
  unsigned short* xbf   = (unsigned short*)(ws + off); off += (size_t)MROWS * D_MODEL * 2;
  unsigned short* qb    = (unsigned short*)(ws + off); off += (size_t)MROWS * D_MODEL * 2;
  unsigned short* kb    = (unsigned short*)(ws + off); off += (size_t)MROWS * D_MODEL * 2;
  unsigned short* vtb   = (unsigned short*)(ws + off); off += (size_t)MROWS * D_MODEL * 2;
  unsigned short* attn_out = xbf;  // x no longer needed after the 3 QKV GEMMs

  hipMemsetAsync(sums, 0, 4 * sizeof(double), stream);
  absmean_kernel<<<dim3(256, 4), 256, 0, stream>>>(wq, wk, wv, wo, sums);
  cvt_bf16_kernel<<<MROWS * D_MODEL / 4 / 256, 256, 0, stream>>>(x, xbf);

  // Q carries 1/sqrt(128) * log2(e) so attention scores are in log2 units (exp2f native)
  const float qfold = 0.08838834764831845f * 1.4426950408889634f;

  const dim3 ggrid(D_MODEL / 128, MROWS / 128);
  quant_kernel<<<WELEMS / 4 / 256, 256, 0, stream>>>(wq, wtern, sums, 0);
  gemm_bt_kernel<0><<<ggrid, 256, 0, stream>>>(xbf, wtern, qb, sums, 0, qfold);
  quant_kernel<<<WELEMS / 4 / 256, 256, 0, stream>>>(wk, wtern, sums, 1);
  gemm_bt_kernel<0><<<ggrid, 256, 0, stream>>>(xbf, wtern, kb, sums, 1, 1.0f);
  quant_kernel<<<WELEMS / 4 / 256, 256, 0, stream>>>(wv, wtern, sums, 2);
  gemm_bt_kernel<1><<<ggrid, 256, 0, stream>>>(xbf, wtern, vtb, sums, 2, 1.0f);

  attn_kernel<<<dim3(16, NHEAD, BATCH), 256, 0, stream>>>(qb, kb, vtb, attn_out);

  quant_kernel<<<WELEMS / 4 / 256, 256, 0, stream>>>(wo, wtern, sums, 3);
  gemm_bt_kernel<2><<<ggrid, 256, 0, stream>>>(attn_out, wtern, out, sums, 3, 1.0f);
}

// Round 10
// 741.356 us; speedup vs baseline: 1.8533x; 1.3333x over previous
//
#include <hip/hip_runtime.h>
#include <stdint.h>

#define D_MODEL 2048
#define NHEAD   16
#define DHEAD   128
#define BATCH   4
#define SEQ     2048
#define MROWS   (BATCH*SEQ)          // 8192
#define WELEMS  (D_MODEL*D_MODEL)    // 4194304
#define NITEMS  2048                 // 32 strips x 64 (b,h)

typedef __attribute__((ext_vector_type(4))) float          f32x4;
typedef __attribute__((ext_vector_type(8))) short          s16x8;
typedef __attribute__((ext_vector_type(4))) unsigned short u16x4;

// ---------- helpers ----------
__device__ __forceinline__ unsigned short f2bf(float f) {
  union { float f; uint32_t u; } v; v.f = f;
  uint32_t r = v.u + 0x7fffu + ((v.u >> 16) & 1u);   // RNE
  return (unsigned short)(r >> 16);
}

__device__ __forceinline__ void load_lds16(const void* g, void* l) {
  // LDS dest is wave-uniform base + lane*16 (HW semantics); global src per-lane.
  __builtin_amdgcn_global_load_lds(
      (__attribute__((address_space(1))) void*)(g),
      (__attribute__((address_space(3))) void*)(l), 16, 0, 0);
}

__device__ __forceinline__ float gamma_of(const double* sums, int gidx) {
  double gs = sums[gidx] * (1.0 / (double)WELEMS);
  if (gs < 1e-5) gs = 1e-5;
  return (float)gs;
}

// ---------- abs-mean reduction (fp64 accumulate, 4 weights) ----------
__global__ __launch_bounds__(256) void absmean_kernel(
    const float* __restrict__ w0, const float* __restrict__ w1,
    const float* __restrict__ w2, const float* __restrict__ w3,
    double* __restrict__ sums) {
  const float* w = blockIdx.y == 0 ? w0 : blockIdx.y == 1 ? w1
                 : blockIdx.y == 2 ? w2 : w3;
  double acc = 0.0;
  const int stride = gridDim.x * blockDim.x;
  for (int i = blockIdx.x * blockDim.x + threadIdx.x; i < WELEMS / 4; i += stride) {
    float4 v = ((const float4*)w)[i];
    acc += (double)fabsf(v.x) + (double)fabsf(v.y) +
           (double)fabsf(v.z) + (double)fabsf(v.w);
  }
  acc += __shfl_xor(acc, 1);  acc += __shfl_xor(acc, 2);  acc += __shfl_xor(acc, 4);
  acc += __shfl_xor(acc, 8);  acc += __shfl_xor(acc, 16); acc += __shfl_xor(acc, 32);
  __shared__ double wsum[4];
  const int lane = threadIdx.x & 63, wave = threadIdx.x >> 6;
  if (lane == 0) wsum[wave] = acc;
  __syncthreads();
  if (threadIdx.x == 0)
    atomicAdd(&sums[blockIdx.y], wsum[0] + wsum[1] + wsum[2] + wsum[3]);
}

// ---------- ternary quantize -> bf16 bits ----------
__global__ __launch_bounds__(256) void quant_kernel(
    const float* __restrict__ wsrc, unsigned short* __restrict__ wt,
    const double* __restrict__ sums, int gidx) {
  const float gf = gamma_of(sums, gidx);
  const int i = blockIdx.x * 256 + threadIdx.x;
  float4 v = ((const float4*)wsrc)[i];
  u16x4 r;
  r[0] = f2bf(fminf(1.f, fmaxf(-1.f, rintf(v.x / gf))));
  r[1] = f2bf(fminf(1.f, fmaxf(-1.f, rintf(v.y / gf))));
  r[2] = f2bf(fminf(1.f, fmaxf(-1.f, rintf(v.z / gf))));
  r[3] = f2bf(fminf(1.f, fmaxf(-1.f, rintf(v.w / gf))));
  ((u16x4*)wt)[i] = r;
}

// ---------- f32 -> bf16 convert ----------
__global__ __launch_bounds__(256) void cvt_bf16_kernel(
    const float* __restrict__ x, unsigned short* __restrict__ xb) {
  const int i = blockIdx.x * 256 + threadIdx.x;
  float4 v = ((const float4*)x)[i];
  u16x4 r;
  r[0] = f2bf(v.x); r[1] = f2bf(v.y); r[2] = f2bf(v.z); r[3] = f2bf(v.w);
  ((u16x4*)xb)[i] = r;
}

// ---------- GEMM: C = (A @ Bt^T) * gamma * escale  (m97 structure: 128x128, BK=32) ----------
// MODE 0: bf16 out (row,col). MODE 1: bf16 out transposed to (b,h,d,t). MODE 2: f32 out.
// Grid is FIXED at (16, 64); blockIdx is XCD-swizzled (T1, bijective since 1024 % 8 == 0).
template <int MODE>
__global__ __launch_bounds__(256) void gemm_bt_kernel(
    const unsigned short* __restrict__ A,
    const unsigned short* __restrict__ Bt,
    void* __restrict__ out,
    const double* __restrict__ sums, int gidx, float escale) {
  constexpr int K = D_MODEL;
  __shared__ unsigned short As[128 * 32];   // [row][32k] 64B rows, linear
  __shared__ unsigned short Bs[128 * 32];
  const int tid = threadIdx.x, lane = tid & 63, wave = tid >> 6;
  const int g = lane >> 4, r15 = lane & 15;
  const int wm = wave >> 1, wn = wave & 1;

  // XCD-aware swizzle: consecutive wg' within one XCD share A/B panels (L2 locality)
  const int lin = blockIdx.y * 16 + blockIdx.x;     // 0..1023
  const int wg  = (lin & 7) * 128 + (lin >> 3);     // bijective (1024 = 8*128)
  const int rowBase = (wg >> 4) * 128, colBase = (wg & 15) * 128;

  f32x4 acc[4][4] = {};

  const int o0 = wave * 1024 + lane * 16;
  const int o1 = 4096 + wave * 1024 + lane * 16;
  const unsigned short* Ap0 = A  + (size_t)(rowBase + (o0 >> 6)) * K + ((o0 >> 4) & 3) * 8;
  const unsigned short* Ap1 = A  + (size_t)(rowBase + (o1 >> 6)) * K + ((o1 >> 4) & 3) * 8;
  const unsigned short* Bp0 = Bt + (size_t)(colBase + (o0 >> 6)) * K + ((o0 >> 4) & 3) * 8;
  const unsigned short* Bp1 = Bt + (size_t)(colBase + (o1 >> 6)) * K + ((o1 >> 4) & 3) * 8;
  char* AsB = (char*)As; char* BsB = (char*)Bs;

  for (int kt = 0; kt < K; kt += 32) {
    load_lds16(Ap0 + kt, AsB + wave * 1024);
    load_lds16(Ap1 + kt, AsB + 4096 + wave * 1024);
    load_lds16(Bp0 + kt, BsB + wave * 1024);
    load_lds16(Bp1 + kt, BsB + 4096 + wave * 1024);
    __syncthreads();
    s16x8 a[4], b[4];
#pragma unroll
    for (int m = 0; m < 4; ++m)
      a[m] = *(const s16x8*)(AsB + (wm * 64 + m * 16 + r15) * 64 + g * 16);
#pragma unroll
    for (int n = 0; n < 4; ++n)
      b[n] = *(const s16x8*)(BsB + (wn * 64 + n * 16 + r15) * 64 + g * 16);
#pragma unroll
    for (int m = 0; m < 4; ++m)
#pragma unroll
      for (int n = 0; n < 4; ++n)
        acc[m][n] = __builtin_amdgcn_mfma_f32_16x16x32_bf16(a[m], b[n], acc[m][n], 0, 0, 0);
    __syncthreads();
  }

  const float scale = gamma_of(sums, gidx) * escale;
#pragma unroll
  for (int m = 0; m < 4; ++m) {
    const int row0 = rowBase + wm * 64 + m * 16 + g * 4;   // C/D: row=(l>>4)*4+j
#pragma unroll
    for (int n = 0; n < 4; ++n) {
      const int col = colBase + wn * 64 + n * 16 + r15;    // C/D: col=l&15
      if constexpr (MODE == 2) {
        float* op = (float*)out;
#pragma unroll
        for (int j = 0; j < 4; ++j)
          op[(size_t)(row0 + j) * D_MODEL + col] = acc[m][n][j] * scale;
      } else if constexpr (MODE == 0) {
        unsigned short* op = (unsigned short*)out;
#pragma unroll
        for (int j = 0; j < 4; ++j)
          op[(size_t)(row0 + j) * D_MODEL + col] = f2bf(acc[m][n][j] * scale);
      } else {  // MODE 1: write V^T laid out (b, h, d, t); 4 j's are contiguous t
        unsigned short* op = (unsigned short*)out;
        const int bb = row0 >> 11, t = row0 & 2047;
        const int hh = col >> 7,  d = col & 127;
        u16x4 r;
#pragma unroll
        for (int j = 0; j < 4; ++j) r[j] = f2bf(acc[m][n][j] * scale);
        *(u16x4*)(op + (((size_t)bb * NHEAD + hh) * DHEAD + d) * SEQ + t) = r;
      }
    }
  }
}

// ---------- causal flash attention (persistent blocks + work-stealing) ----------
// q: (B*T,2048) bf16 pre-scaled by gamma_q/sqrt(128)*log2(e). k: (B*T,2048) bf16 (gamma_k folded).
// vt: (B,H,128,T) bf16. out: (B*T,2048) bf16.
// R0 geometry (fastest measured): 256 threads = 4 waves x 16 q-rows, 64-row q-strips,
// K AND V staged in 40KB static LDS, 2 barriers/tile, single-strip state (64 VGPR, 4 blocks/CU).
// NEW: 1024 persistent blocks (exactly 4/CU residency) grab (strip,bh) items from a global
// atomic counter, HEAVY-FIRST (LPT): item i -> qs = 31-(i>>6), bh = i&63. This keeps R8's
// lesson: all resident blocks sweep KV tiles 0,1,2,.. in near-lockstep (L3-served staging,
// FETCH ~260MB not 1.1GB) while greedy scheduling kills R0's tail imbalance.
// Scores in log2 units (exp2f); defer-max (T13); mask only diagonal tile; setprio on MFMA.
// LDS tiles XOR-swizzled byte^=((row&7)<<4) via pre-swizzled global source (rule #21).
__global__ __launch_bounds__(256, 4) void attn_kernel(
    const unsigned short* __restrict__ qg,
    const unsigned short* __restrict__ kg,
    const unsigned short* __restrict__ vtg,
    unsigned short* __restrict__ og,
    int* __restrict__ counter) {
  __shared__ unsigned short Ks[64 * 128];    // [key][d]  256B rows, 16KB
  __shared__ unsigned short Vts[128 * 64];   // [d][kv]   128B rows, 16KB
  __shared__ unsigned short Ps[4][1024];     // per-wave [q16][kv64] 128B rows, 8KB
  __shared__ int s_item;

  const int tid = threadIdx.x, lane = tid & 63, wave = tid >> 6;
  const int g = lane >> 4, r15 = lane & 15;

  char* KsB = (char*)Ks; char* VtsB = (char*)Vts; char* PsB = (char*)(Ps[wave]);

  for (;;) {
    if (tid == 0) s_item = atomicAdd(counter, 1);
    __syncthreads();                         // publish s_item
    const int item = s_item;
    __syncthreads();                         // all read before next overwrite
    if (item >= NITEMS) break;               // block-uniform exit

    const int qs = 31 - (item >> 6);         // heavy strips first (LPT)
    const int bh = item & 63;
    const int b = bh >> 4, h = bh & 15;

    const unsigned short* kbase = kg + (size_t)b * SEQ * D_MODEL + h * DHEAD;
    const unsigned short* vbase = vtg + (size_t)(b * NHEAD + h) * DHEAD * SEQ;

    // Q fragments (A-layout: row=l&15, k=(l>>4)*8), hoisted for the strip
    s16x8 qf[4];
    {
      const unsigned short* qbase =
          qg + (size_t)(b * SEQ + qs * 64 + wave * 16 + r15) * D_MODEL + h * DHEAD;
#pragma unroll
      for (int c = 0; c < 4; ++c) qf[c] = *(const s16x8*)(qbase + c * 32 + g * 8);
    }

    f32x4 oacc[8] = {};
    float mr[4], lr[4];
#pragma unroll
    for (int j = 0; j < 4; ++j) { mr[j] = -1e30f; lr[j] = 0.f; }

    const int nt = qs + 1;                   // KV tiles for this strip

#pragma unroll 1
    for (int t = 0; t < nt; ++t) {
      // ---- stage K (16KB) and Vt (16KB): linear LDS, pre-swizzled global source
#pragma unroll
      for (int rnd = 0; rnd < 4; ++rnd) {
        const int ob = rnd * 4096 + wave * 1024 + lane * 16;
        const int krow = ob >> 8;
        const int ks = (ob & 255) ^ ((krow & 7) << 4);
        load_lds16(kbase + (size_t)(t * 64 + krow) * D_MODEL + (ks >> 1),
                   KsB + rnd * 4096 + wave * 1024);
        const int drow = ob >> 7;
        const int vs = (ob & 127) ^ ((drow & 7) << 4);
        load_lds16(vbase + (size_t)drow * SEQ + t * 64 + (vs >> 1),
                   VtsB + rnd * 4096 + wave * 1024);
      }
      __syncthreads();

      // ---- S = Q K^T  (16 q-rows x 64 keys, log2 units: scale folded into Q)
      f32x4 s[4] = {};
      __builtin_amdgcn_s_setprio(1);
#pragma unroll
      for (int c = 0; c < 4; ++c) {
#pragma unroll
        for (int n = 0; n < 4; ++n) {
          const int key = n * 16 + r15;
          const int baddr = (((key << 8) | (c << 6) | (g << 4))) ^ ((key & 7) << 4);
          s16x8 kf = *(const s16x8*)(KsB + baddr);
          s[n] = __builtin_amdgcn_mfma_f32_16x16x32_bf16(qf[c], kf, s[n], 0, 0, 0);
        }
      }
      __builtin_amdgcn_s_setprio(0);

      if (t == qs) {                         // only the diagonal tile needs the causal mask
        const int q0 = qs * 64 + wave * 16 + g * 4;
        const int k0 = t * 64 + r15;
#pragma unroll
        for (int n = 0; n < 4; ++n)
#pragma unroll
          for (int j = 0; j < 4; ++j)
            if (k0 + n * 16 > q0 + j) s[n][j] = -1e30f;
      }
      float pm[4];
#pragma unroll
      for (int j = 0; j < 4; ++j)
        pm[j] = fmaxf(fmaxf(s[0][j], s[1][j]), fmaxf(s[2][j], s[3][j]));
#pragma unroll
      for (int j = 0; j < 4; ++j) {
        pm[j] = fmaxf(pm[j], __shfl_xor(pm[j], 1));
        pm[j] = fmaxf(pm[j], __shfl_xor(pm[j], 2));
        pm[j] = fmaxf(pm[j], __shfl_xor(pm[j], 4));
        pm[j] = fmaxf(pm[j], __shfl_xor(pm[j], 8));
      }
      // defer-max (T13): skip rescale while max growth < 8 (log2 units, P <= 256)
      bool ok = pm[0] <= mr[0] + 8.f && pm[1] <= mr[1] + 8.f &&
                pm[2] <= mr[2] + 8.f && pm[3] <= mr[3] + 8.f;
      if (!__all(ok)) {
#pragma unroll
        for (int j = 0; j < 4; ++j) {
          const float mn = fmaxf(mr[j], pm[j]);
          const float rf = exp2f(mr[j] - mn);
          mr[j] = mn;
          lr[j] *= rf;
#pragma unroll
          for (int n2 = 0; n2 < 8; ++n2) oacc[n2][j] *= rf;
        }
      }
      // ---- P = exp2(S-m): row-sum + bf16 P into swizzled per-wave LDS
      float psum[4] = {0.f, 0.f, 0.f, 0.f};
#pragma unroll
      for (int n = 0; n < 4; ++n) {
        const int keyl = n * 16 + r15;
#pragma unroll
        for (int j = 0; j < 4; ++j) {
          const float p = exp2f(s[n][j] - mr[j]);
          psum[j] += p;
          const int row = g * 4 + j;
          const int baddr = ((row << 7) | (keyl << 1)) ^ ((row & 7) << 4);
          *(unsigned short*)(PsB + baddr) = f2bf(p);
        }
      }
#pragma unroll
      for (int j = 0; j < 4; ++j) {
        psum[j] += __shfl_xor(psum[j], 1);
        psum[j] += __shfl_xor(psum[j], 2);
        psum[j] += __shfl_xor(psum[j], 4);
        psum[j] += __shfl_xor(psum[j], 8);
        lr[j] += psum[j];
      }
      // ---- O += P V   (A = P from per-wave LDS, B = Vt rows; in-wave order is safe)
      __builtin_amdgcn_s_setprio(1);
#pragma unroll
      for (int c2 = 0; c2 < 2; ++c2) {
        const int baddr_p = (((r15 << 7) | (c2 << 6) | (g << 4))) ^ ((r15 & 7) << 4);
        s16x8 pa = *(const s16x8*)(PsB + baddr_p);
#pragma unroll
        for (int n2 = 0; n2 < 8; ++n2) {
          const int d = n2 * 16 + r15;
          const int baddr_v = (((d << 7) | (c2 << 6) | (g << 4))) ^ ((d & 7) << 4);
          s16x8 vf = *(const s16x8*)(VtsB + baddr_v);
          oacc[n2] = __builtin_amdgcn_mfma_f32_16x16x32_bf16(pa, vf, oacc[n2], 0, 0, 0);
        }
      }
      __builtin_amdgcn_s_setprio(0);
      __syncthreads();   // guard Ks/Vts before next tile's staging
    }

    // ---- normalize + write (b,t,h,d)
    unsigned short* obase =
        og + (size_t)(b * SEQ + qs * 64 + wave * 16 + g * 4) * D_MODEL + h * DHEAD;
    float inv[4];
#pragma unroll
    for (int j = 0; j < 4; ++j) inv[j] = 1.f / lr[j];
#pragma unroll
    for (int n2 = 0; n2 < 8; ++n2) {
      const int d = n2 * 16 + r15;
#pragma unroll
      for (int j = 0; j < 4; ++j)
        obase[(size_t)j * D_MODEL + d] = f2bf(oacc[n2][j] * inv[j]);
    }
  }
}

// ---------- launch ----------
extern "C" void kernel_launch(void* const* d_in, const int* in_sizes, int n_in,
                              void* d_out, int out_size, void* d_ws, size_t ws_size,
                              hipStream_t stream) {
  const float* x  = (const float*)d_in[0];
  const float* wq = (const float*)d_in[1];
  const float* wk = (const float*)d_in[2];
  const float* wv = (const float*)d_in[3];
  const float* wo = (const float*)d_in[4];
  float* out = (float*)d_out;

  char* ws = (char*)d_ws;
  double* sums = (double*)ws;                 // 4 doubles at ws+0
  int* cnt = (int*)(ws + 64);                 // work-stealing counter at ws+64
  size_t off = 256;
  unsigned short* wtern = (unsigned short*)(ws + off); off += (size_t)WELEMS * 2;
  unsigned short* xbf   = (unsigned short*)(ws + off); off += (size_t)MROWS * D_MODEL * 2;
  unsigned short* qb    = (unsigned short*)(ws + off); off += (size_t)MROWS * D_MODEL * 2;
  unsigned short* kb    = (unsigned short*)(ws + off); off += (size_t)MROWS * D_MODEL * 2;
  unsigned short* vtb   = (unsigned short*)(ws + off); off += (size_t)MROWS * D_MODEL * 2;
  unsigned short* attn_out = xbf;  // x no longer needed after the 3 QKV GEMMs

  hipMemsetAsync(ws, 0, 256, stream);         // zeroes sums + counter
  absmean_kernel<<<dim3(256, 4), 256, 0, stream>>>(wq, wk, wv, wo, sums);
  cvt_bf16_kernel<<<MROWS * D_MODEL / 4 / 256, 256, 0, stream>>>(x, xbf);

  // Q carries 1/sqrt(128) * log2(e) so attention scores are in log2 units (exp2f native)
  const float qfold = 0.08838834764831845f * 1.4426950408889634f;

  const dim3 ggrid(D_MODEL / 128, MROWS / 128);
  quant_kernel<<<WELEMS / 4 / 256, 256, 0, stream>>>(wq, wtern, sums, 0);
  gemm_bt_kernel<0><<<ggrid, 256, 0, stream>>>(xbf, wtern, qb, sums, 0, qfold);
  quant_kernel<<<WELEMS / 4 / 256, 256, 0, stream>>>(wk, wtern, sums, 1);
  gemm_bt_kernel<0><<<ggrid, 256, 0, stream>>>(xbf, wtern, kb, sums, 1, 1.0f);
  quant_kernel<<<WELEMS / 4 / 256, 256, 0, stream>>>(wv, wtern, sums, 2);
  gemm_bt_kernel<1><<<ggrid, 256, 0, stream>>>(xbf, wtern, vtb, sums, 2, 1.0f);

  attn_kernel<<<dim3(1024), 256, 0, stream>>>(qb, kb, vtb, attn_out, cnt);

  quant_kernel<<<WELEMS / 4 / 256, 256, 0, stream>>>(wo, wtern, sums, 3);
  gemm_bt_kernel<2><<<ggrid, 256, 0, stream>>>(attn_out, wtern, out, sums, 3, 1.0f);
}

// Round 11
// 633.773 us; speedup vs baseline: 2.1680x; 1.1698x over previous
//
#include <hip/hip_runtime.h>
#include <stdint.h>

#define D_MODEL 2048
#define NHEAD   16
#define DHEAD   128
#define BATCH   4
#define SEQ     2048
#define MROWS   (BATCH*SEQ)          // 8192
#define WELEMS  (D_MODEL*D_MODEL)    // 4194304
#define NITEMS  2048                 // 32 strips x 64 (b,h)

typedef __attribute__((ext_vector_type(4))) float          f32x4;
typedef __attribute__((ext_vector_type(8))) short          s16x8;
typedef __attribute__((ext_vector_type(4))) unsigned short u16x4;

// ---------- helpers ----------
__device__ __forceinline__ unsigned short f2bf(float f) {
  union { float f; uint32_t u; } v; v.f = f;
  uint32_t r = v.u + 0x7fffu + ((v.u >> 16) & 1u);   // RNE
  return (unsigned short)(r >> 16);
}

__device__ __forceinline__ void load_lds16(const void* g, void* l) {
  // LDS dest is wave-uniform base + lane*16 (HW semantics); global src per-lane.
  __builtin_amdgcn_global_load_lds(
      (__attribute__((address_space(1))) void*)(g),
      (__attribute__((address_space(3))) void*)(l), 16, 0, 0);
}

__device__ __forceinline__ float gamma_of(const double* sums, int gidx) {
  double gs = sums[gidx] * (1.0 / (double)WELEMS);
  if (gs < 1e-5) gs = 1e-5;
  return (float)gs;
}

// ---------- abs-mean reduction (fp64 accumulate, 4 weights) ----------
__global__ __launch_bounds__(256) void absmean_kernel(
    const float* __restrict__ w0, const float* __restrict__ w1,
    const float* __restrict__ w2, const float* __restrict__ w3,
    double* __restrict__ sums) {
  const float* w = blockIdx.y == 0 ? w0 : blockIdx.y == 1 ? w1
                 : blockIdx.y == 2 ? w2 : w3;
  double acc = 0.0;
  const int stride = gridDim.x * blockDim.x;
  for (int i = blockIdx.x * blockDim.x + threadIdx.x; i < WELEMS / 4; i += stride) {
    float4 v = ((const float4*)w)[i];
    acc += (double)fabsf(v.x) + (double)fabsf(v.y) +
           (double)fabsf(v.z) + (double)fabsf(v.w);
  }
  acc += __shfl_xor(acc, 1);  acc += __shfl_xor(acc, 2);  acc += __shfl_xor(acc, 4);
  acc += __shfl_xor(acc, 8);  acc += __shfl_xor(acc, 16); acc += __shfl_xor(acc, 32);
  __shared__ double wsum[4];
  const int lane = threadIdx.x & 63, wave = threadIdx.x >> 6;
  if (lane == 0) wsum[wave] = acc;
  __syncthreads();
  if (threadIdx.x == 0)
    atomicAdd(&sums[blockIdx.y], wsum[0] + wsum[1] + wsum[2] + wsum[3]);
}

// ---------- ternary quantize -> bf16 bits ----------
__global__ __launch_bounds__(256) void quant_kernel(
    const float* __restrict__ wsrc, unsigned short* __restrict__ wt,
    const double* __restrict__ sums, int gidx) {
  const float gf = gamma_of(sums, gidx);
  const int i = blockIdx.x * 256 + threadIdx.x;
  float4 v = ((const float4*)wsrc)[i];
  u16x4 r;
  r[0] = f2bf(fminf(1.f, fmaxf(-1.f, rintf(v.x / gf))));
  r[1] = f2bf(fminf(1.f, fmaxf(-1.f, rintf(v.y / gf))));
  r[2] = f2bf(fminf(1.f, fmaxf(-1.f, rintf(v.z / gf))));
  r[3] = f2bf(fminf(1.f, fmaxf(-1.f, rintf(v.w / gf))));
  ((u16x4*)wt)[i] = r;
}

// ---------- f32 -> bf16 convert ----------
__global__ __launch_bounds__(256) void cvt_bf16_kernel(
    const float* __restrict__ x, unsigned short* __restrict__ xb) {
  const int i = blockIdx.x * 256 + threadIdx.x;
  float4 v = ((const float4*)x)[i];
  u16x4 r;
  r[0] = f2bf(v.x); r[1] = f2bf(v.y); r[2] = f2bf(v.z); r[3] = f2bf(v.w);
  ((u16x4*)xb)[i] = r;
}

// ---------- GEMM: C = (A @ Bt^T) * gamma * escale ----------
// 256x256 tile, BK=32, 8 waves (2M x 4N), per-wave output 128x64 (8x4 frags).
// 3-buffer LDS rotation (3 x 32KB = 96KB dynamic) with COUNTED vmcnt (T3/T4):
//   while computing tile t (buf t%3), tile t+2's loads go to buf (t+2)%3;
//   boundary: each wave waits vmcnt(4) (own t+2 loads stay in flight) BEFORE the raw
//   s_barrier -> every wave's t+1 loads are complete & visible; never drains to 0.
// T2: LDS col-byte XOR swizzle ((row&3)<<4) applied to stage SOURCE and ds_read (rule #21):
//   8-way bank conflict -> 4-way (below MFMA cycle floor).
// T5: setprio(1) around each 16-MFMA cluster.
// Grid: 256 blocks (1/CU), XCD-swizzled (bijective, 256%8==0).
// MODE 0: bf16 out (row,col). MODE 1: bf16 out transposed to (b,h,d,t). MODE 2: f32 out.
template <int MODE>
__global__ __launch_bounds__(512, 2) void gemm_bt_kernel(
    const unsigned short* __restrict__ A,
    const unsigned short* __restrict__ Bt,
    void* __restrict__ out,
    const double* __restrict__ sums, int gidx, float escale) {
  constexpr int K = D_MODEL;
  constexpr int NT = K / 32;                 // 64 K-tiles
  extern __shared__ char smem[];             // 3 x (A 16KB | B 16KB)

  const int tid = threadIdx.x, lane = tid & 63, wave = tid >> 6;
  const int g = lane >> 4, r15 = lane & 15;
  const int wm = wave >> 2, wn = wave & 3;   // 2M x 4N wave grid

  const int wgid = (blockIdx.x & 7) * 32 + (blockIdx.x >> 3);   // XCD swizzle
  const int rowBase = (wgid >> 3) * 256, colBase = (wgid & 7) * 256;

  // staging addresses: thread stages 16B at linear o0 (rows 0-127) and o1 (rows 128-255)
  // of each 16KB [256][32]bf16 tile; global source pre-swizzled col ^= (row&3)<<4.
  const int o0 = tid * 16, o1 = 8192 + tid * 16;
  const int sr0 = o0 >> 6, sc0 = (o0 & 63) ^ ((sr0 & 3) << 4);
  const int sr1 = o1 >> 6, sc1 = (o1 & 63) ^ ((sr1 & 3) << 4);
  const unsigned short* ApS0 = A  + (size_t)(rowBase + sr0) * K + (sc0 >> 1);
  const unsigned short* ApS1 = A  + (size_t)(rowBase + sr1) * K + (sc1 >> 1);
  const unsigned short* BpS0 = Bt + (size_t)(colBase + sr0) * K + (sc0 >> 1);
  const unsigned short* BpS1 = Bt + (size_t)(colBase + sr1) * K + (sc1 >> 1);

  char* b0 = smem; char* b1 = smem + 32768; char* b2 = smem + 65536;
  const int woff = wave * 1024;

  // read-side swizzle: row&3 == r15&3 for every frag (frag rows are 16-aligned + r15)
  const int sw = (g * 16) ^ ((r15 & 3) << 4);
  const int arow = wm * 128 + r15;           // + fr*16
  const int brow = wn * 64 + r15;            // + fn*16

  f32x4 acc[8][4] = {};

  // ---- prologue: stage tiles 0,1; wait tile 0; barrier
  load_lds16(ApS0, b0 + woff);          load_lds16(ApS1, b0 + 8192 + woff);
  load_lds16(BpS0, b0 + 16384 + woff);  load_lds16(BpS1, b0 + 24576 + woff);
  load_lds16(ApS0 + 32, b1 + woff);         load_lds16(ApS1 + 32, b1 + 8192 + woff);
  load_lds16(BpS0 + 32, b1 + 16384 + woff); load_lds16(BpS1 + 32, b1 + 24576 + woff);
  asm volatile("s_waitcnt vmcnt(4)" ::: "memory");
  __builtin_amdgcn_sched_barrier(0);
  __builtin_amdgcn_s_barrier();
  __builtin_amdgcn_sched_barrier(0);

#pragma unroll 1
  for (int t = 0; t < NT; ++t) {
    const bool pf = (t + 2 < NT);
    const int koff = (t + 2) * 32;

    // ---- phase 0: issue A-prefetch, read B frags + A fr0-3, 16 MFMA
    if (pf) {
      load_lds16(ApS0 + koff, b2 + woff);
      load_lds16(ApS1 + koff, b2 + 8192 + woff);
    }
    s16x8 bf[4], af[4];
#pragma unroll
    for (int fn = 0; fn < 4; ++fn)
      bf[fn] = *(const s16x8*)(b0 + 16384 + (brow + fn * 16) * 64 + sw);
#pragma unroll
    for (int fr = 0; fr < 4; ++fr)
      af[fr] = *(const s16x8*)(b0 + (arow + fr * 16) * 64 + sw);
    __builtin_amdgcn_s_setprio(1);
#pragma unroll
    for (int fr = 0; fr < 4; ++fr)
#pragma unroll
      for (int fn = 0; fn < 4; ++fn)
        acc[fr][fn] = __builtin_amdgcn_mfma_f32_16x16x32_bf16(af[fr], bf[fn], acc[fr][fn], 0, 0, 0);
    __builtin_amdgcn_s_setprio(0);

    // ---- phase 1: issue B-prefetch, read A fr4-7, 16 MFMA
    if (pf) {
      load_lds16(BpS0 + koff, b2 + 16384 + woff);
      load_lds16(BpS1 + koff, b2 + 24576 + woff);
    }
#pragma unroll
    for (int fr = 0; fr < 4; ++fr)
      af[fr] = *(const s16x8*)(b0 + (arow + (fr + 4) * 16) * 64 + sw);
    __builtin_amdgcn_s_setprio(1);
#pragma unroll
    for (int fr = 0; fr < 4; ++fr)
#pragma unroll
      for (int fn = 0; fn < 4; ++fn)
        acc[fr + 4][fn] = __builtin_amdgcn_mfma_f32_16x16x32_bf16(af[fr], bf[fn], acc[fr + 4][fn], 0, 0, 0);
    __builtin_amdgcn_s_setprio(0);

    // ---- boundary: counted wait (own t+2 loads stay in flight), raw barrier, rotate
    if (pf) asm volatile("s_waitcnt vmcnt(4)" ::: "memory");
    else    asm volatile("s_waitcnt vmcnt(0)" ::: "memory");
    __builtin_amdgcn_sched_barrier(0);
    __builtin_amdgcn_s_barrier();
    __builtin_amdgcn_sched_barrier(0);
    char* tmp = b0; b0 = b1; b1 = b2; b2 = tmp;
  }

  // ---- epilogue
  const float scale = gamma_of(sums, gidx) * escale;
#pragma unroll
  for (int fr = 0; fr < 8; ++fr) {
    const int row0 = rowBase + wm * 128 + fr * 16 + g * 4;   // C/D: row=(l>>4)*4+j
#pragma unroll
    for (int fn = 0; fn < 4; ++fn) {
      const int col = colBase + wn * 64 + fn * 16 + r15;     // C/D: col=l&15
      if constexpr (MODE == 2) {
        float* op = (float*)out;
#pragma unroll
        for (int j = 0; j < 4; ++j)
          op[(size_t)(row0 + j) * D_MODEL + col] = acc[fr][fn][j] * scale;
      } else if constexpr (MODE == 0) {
        unsigned short* op = (unsigned short*)out;
#pragma unroll
        for (int j = 0; j < 4; ++j)
          op[(size_t)(row0 + j) * D_MODEL + col] = f2bf(acc[fr][fn][j] * scale);
      } else {  // MODE 1: write V^T laid out (b, h, d, t); 4 j's are contiguous t
        unsigned short* op = (unsigned short*)out;
        const int bb = row0 >> 11, tt = row0 & 2047;
        const int hh = col >> 7,  d = col & 127;
        u16x4 r;
#pragma unroll
        for (int j = 0; j < 4; ++j) r[j] = f2bf(acc[fr][fn][j] * scale);
        *(u16x4*)(op + (((size_t)bb * NHEAD + hh) * DHEAD + d) * SEQ + tt) = r;
      }
    }
  }
}

// ---------- causal flash attention (persistent blocks + work-stealing, R9 measured) ----------
__global__ __launch_bounds__(256, 4) void attn_kernel(
    const unsigned short* __restrict__ qg,
    const unsigned short* __restrict__ kg,
    const unsigned short* __restrict__ vtg,
    unsigned short* __restrict__ og,
    int* __restrict__ counter) {
  __shared__ unsigned short Ks[64 * 128];    // [key][d]  256B rows, 16KB
  __shared__ unsigned short Vts[128 * 64];   // [d][kv]   128B rows, 16KB
  __shared__ unsigned short Ps[4][1024];     // per-wave [q16][kv64] 128B rows, 8KB
  __shared__ int s_item;

  const int tid = threadIdx.x, lane = tid & 63, wave = tid >> 6;
  const int g = lane >> 4, r15 = lane & 15;

  char* KsB = (char*)Ks; char* VtsB = (char*)Vts; char* PsB = (char*)(Ps[wave]);

  for (;;) {
    if (tid == 0) s_item = atomicAdd(counter, 1);
    __syncthreads();                         // publish s_item
    const int item = s_item;
    __syncthreads();                         // all read before next overwrite
    if (item >= NITEMS) break;               // block-uniform exit

    const int qs = 31 - (item >> 6);         // heavy strips first (LPT)
    const int bh = item & 63;
    const int b = bh >> 4, h = bh & 15;

    const unsigned short* kbase = kg + (size_t)b * SEQ * D_MODEL + h * DHEAD;
    const unsigned short* vbase = vtg + (size_t)(b * NHEAD + h) * DHEAD * SEQ;

    // Q fragments (A-layout: row=l&15, k=(l>>4)*8), hoisted for the strip
    s16x8 qf[4];
    {
      const unsigned short* qbase =
          qg + (size_t)(b * SEQ + qs * 64 + wave * 16 + r15) * D_MODEL + h * DHEAD;
#pragma unroll
      for (int c = 0; c < 4; ++c) qf[c] = *(const s16x8*)(qbase + c * 32 + g * 8);
    }

    f32x4 oacc[8] = {};
    float mr[4], lr[4];
#pragma unroll
    for (int j = 0; j < 4; ++j) { mr[j] = -1e30f; lr[j] = 0.f; }

    const int nt = qs + 1;                   // KV tiles for this strip

#pragma unroll 1
    for (int t = 0; t < nt; ++t) {
      // ---- stage K (16KB) and Vt (16KB): linear LDS, pre-swizzled global source
#pragma unroll
      for (int rnd = 0; rnd < 4; ++rnd) {
        const int ob = rnd * 4096 + wave * 1024 + lane * 16;
        const int krow = ob >> 8;
        const int ks = (ob & 255) ^ ((krow & 7) << 4);
        load_lds16(kbase + (size_t)(t * 64 + krow) * D_MODEL + (ks >> 1),
                   KsB + rnd * 4096 + wave * 1024);
        const int drow = ob >> 7;
        const int vs = (ob & 127) ^ ((drow & 7) << 4);
        load_lds16(vbase + (size_t)drow * SEQ + t * 64 + (vs >> 1),
                   VtsB + rnd * 4096 + wave * 1024);
      }
      __syncthreads();

      // ---- S = Q K^T  (16 q-rows x 64 keys, log2 units: scale folded into Q)
      f32x4 s[4] = {};
      __builtin_amdgcn_s_setprio(1);
#pragma unroll
      for (int c = 0; c < 4; ++c) {
#pragma unroll
        for (int n = 0; n < 4; ++n) {
          const int key = n * 16 + r15;
          const int baddr = (((key << 8) | (c << 6) | (g << 4))) ^ ((key & 7) << 4);
          s16x8 kf = *(const s16x8*)(KsB + baddr);
          s[n] = __builtin_amdgcn_mfma_f32_16x16x32_bf16(qf[c], kf, s[n], 0, 0, 0);
        }
      }
      __builtin_amdgcn_s_setprio(0);

      if (t == qs) {                         // only the diagonal tile needs the causal mask
        const int q0 = qs * 64 + wave * 16 + g * 4;
        const int k0 = t * 64 + r15;
#pragma unroll
        for (int n = 0; n < 4; ++n)
#pragma unroll
          for (int j = 0; j < 4; ++j)
            if (k0 + n * 16 > q0 + j) s[n][j] = -1e30f;
      }
      float pm[4];
#pragma unroll
      for (int j = 0; j < 4; ++j)
        pm[j] = fmaxf(fmaxf(s[0][j], s[1][j]), fmaxf(s[2][j], s[3][j]));
#pragma unroll
      for (int j = 0; j < 4; ++j) {
        pm[j] = fmaxf(pm[j], __shfl_xor(pm[j], 1));
        pm[j] = fmaxf(pm[j], __shfl_xor(pm[j], 2));
        pm[j] = fmaxf(pm[j], __shfl_xor(pm[j], 4));
        pm[j] = fmaxf(pm[j], __shfl_xor(pm[j], 8));
      }
      // defer-max (T13): skip rescale while max growth < 8 (log2 units, P <= 256)
      bool ok = pm[0] <= mr[0] + 8.f && pm[1] <= mr[1] + 8.f &&
                pm[2] <= mr[2] + 8.f && pm[3] <= mr[3] + 8.f;
      if (!__all(ok)) {
#pragma unroll
        for (int j = 0; j < 4; ++j) {
          const float mn = fmaxf(mr[j], pm[j]);
          const float rf = exp2f(mr[j] - mn);
          mr[j] = mn;
          lr[j] *= rf;
#pragma unroll
          for (int n2 = 0; n2 < 8; ++n2) oacc[n2][j] *= rf;
        }
      }
      // ---- P = exp2(S-m): row-sum + bf16 P into swizzled per-wave LDS
      float psum[4] = {0.f, 0.f, 0.f, 0.f};
#pragma unroll
      for (int n = 0; n < 4; ++n) {
        const int keyl = n * 16 + r15;
#pragma unroll
        for (int j = 0; j < 4; ++j) {
          const float p = exp2f(s[n][j] - mr[j]);
          psum[j] += p;
          const int row = g * 4 + j;
          const int baddr = ((row << 7) | (keyl << 1)) ^ ((row & 7) << 4);
          *(unsigned short*)(PsB + baddr) = f2bf(p);
        }
      }
#pragma unroll
      for (int j = 0; j < 4; ++j) {
        psum[j] += __shfl_xor(psum[j], 1);
        psum[j] += __shfl_xor(psum[j], 2);
        psum[j] += __shfl_xor(psum[j], 4);
        psum[j] += __shfl_xor(psum[j], 8);
        lr[j] += psum[j];
      }
      // ---- O += P V   (A = P from per-wave LDS, B = Vt rows; in-wave order is safe)
      __builtin_amdgcn_s_setprio(1);
#pragma unroll
      for (int c2 = 0; c2 < 2; ++c2) {
        const int baddr_p = (((r15 << 7) | (c2 << 6) | (g << 4))) ^ ((r15 & 7) << 4);
        s16x8 pa = *(const s16x8*)(PsB + baddr_p);
#pragma unroll
        for (int n2 = 0; n2 < 8; ++n2) {
          const int d = n2 * 16 + r15;
          const int baddr_v = (((d << 7) | (c2 << 6) | (g << 4))) ^ ((d & 7) << 4);
          s16x8 vf = *(const s16x8*)(VtsB + baddr_v);
          oacc[n2] = __builtin_amdgcn_mfma_f32_16x16x32_bf16(pa, vf, oacc[n2], 0, 0, 0);
        }
      }
      __builtin_amdgcn_s_setprio(0);
      __syncthreads();   // guard Ks/Vts before next tile's staging
    }

    // ---- normalize + write (b,t,h,d)
    unsigned short* obase =
        og + (size_t)(b * SEQ + qs * 64 + wave * 16 + g * 4) * D_MODEL + h * DHEAD;
    float inv[4];
#pragma unroll
    for (int j = 0; j < 4; ++j) inv[j] = 1.f / lr[j];
#pragma unroll
    for (int n2 = 0; n2 < 8; ++n2) {
      const int d = n2 * 16 + r15;
#pragma unroll
      for (int j = 0; j < 4; ++j)
        obase[(size_t)j * D_MODEL + d] = f2bf(oacc[n2][j] * inv[j]);
    }
  }
}

// ---------- launch ----------
extern "C" void kernel_launch(void* const* d_in, const int* in_sizes, int n_in,
                              void* d_out, int out_size, void* d_ws, size_t ws_size,
                              hipStream_t stream) {
  const float* x  = (const float*)d_in[0];
  const float* wq = (const float*)d_in[1];
  const float* wk = (const float*)d_in[2];
  const float* wv = (const float*)d_in[3];
  const float* wo = (const float*)d_in[4];
  float* out = (float*)d_out;

  char* ws = (char*)d_ws;
  double* sums = (double*)ws;                 // 4 doubles at ws+0
  int* cnt = (int*)(ws + 64);                 // work-stealing counter at ws+64
  size_t off = 256;
  unsigned short* wtern = (unsigned short*)(ws + off); off += (size_t)WELEMS * 2;
  unsigned short* xbf   = (unsigned short*)(ws + off); off += (size_t)MROWS * D_MODEL * 2;
  unsigned short* qb    = (unsigned short*)(ws + off); off += (size_t)MROWS * D_MODEL * 2;
  unsigned short* kb    = (unsigned short*)(ws + off); off += (size_t)MROWS * D_MODEL * 2;
  unsigned short* vtb   = (unsigned short*)(ws + off); off += (size_t)MROWS * D_MODEL * 2;
  unsigned short* attn_out = xbf;  // x no longer needed after the 3 QKV GEMMs

  hipMemsetAsync(ws, 0, 256, stream);         // zeroes sums + counter
  absmean_kernel<<<dim3(256, 4), 256, 0, stream>>>(wq, wk, wv, wo, sums);
  cvt_bf16_kernel<<<MROWS * D_MODEL / 4 / 256, 256, 0, stream>>>(x, xbf);

  // Q carries 1/sqrt(128) * log2(e) so attention scores are in log2 units (exp2f native)
  const float qfold = 0.08838834764831845f * 1.4426950408889634f;

  const int ggrid = (MROWS / 256) * (D_MODEL / 256);   // 256 blocks, 1/CU
  const int glds = 98304;                              // 3 x 32KB rotation buffers
  quant_kernel<<<WELEMS / 4 / 256, 256, 0, stream>>>(wq, wtern, sums, 0);
  gemm_bt_kernel<0><<<ggrid, 512, glds, stream>>>(xbf, wtern, qb, sums, 0, qfold);
  quant_kernel<<<WELEMS / 4 / 256, 256, 0, stream>>>(wk, wtern, sums, 1);
  gemm_bt_kernel<0><<<ggrid, 512, glds, stream>>>(xbf, wtern, kb, sums, 1, 1.0f);
  quant_kernel<<<WELEMS / 4 / 256, 256, 0, stream>>>(wv, wtern, sums, 2);
  gemm_bt_kernel<1><<<ggrid, 512, glds, stream>>>(xbf, wtern, vtb, sums, 2, 1.0f);

  attn_kernel<<<dim3(1024), 256, 0, stream>>>(qb, kb, vtb, attn_out, cnt);

  quant_kernel<<<WELEMS / 4 / 256, 256, 0, stream>>>(wo, wtern, sums, 3);
  gemm_bt_kernel<2><<<ggrid, 512, glds, stream>>>(attn_out, wtern, out, sums, 3, 1.0f);
}

// Round 12
// 612.983 us; speedup vs baseline: 2.2415x; 1.0339x over previous
//
#include <hip/hip_runtime.h>
#include <stdint.h>

#define D_MODEL 2048
#define NHEAD   16
#define DHEAD   128
#define BATCH   4
#define SEQ     2048
#define MROWS   (BATCH*SEQ)          // 8192
#define WELEMS  (D_MODEL*D_MODEL)    // 4194304
#define NITEMS  2048                 // 32 strips x 64 (b,h)

typedef __attribute__((ext_vector_type(4))) float          f32x4;
typedef __attribute__((ext_vector_type(8))) short          s16x8;
typedef __attribute__((ext_vector_type(4))) unsigned short u16x4;

// ---------- helpers ----------
__device__ __forceinline__ unsigned short f2bf(float f) {
  union { float f; uint32_t u; } v; v.f = f;
  uint32_t r = v.u + 0x7fffu + ((v.u >> 16) & 1u);   // RNE
  return (unsigned short)(r >> 16);
}

__device__ __forceinline__ void load_lds16(const void* g, void* l) {
  // LDS dest is wave-uniform base + lane*16 (HW semantics); global src per-lane.
  __builtin_amdgcn_global_load_lds(
      (__attribute__((address_space(1))) void*)(g),
      (__attribute__((address_space(3))) void*)(l), 16, 0, 0);
}

__device__ __forceinline__ float gamma_of(const double* sums, int gidx) {
  double gs = sums[gidx] * (1.0 / (double)WELEMS);
  if (gs < 1e-5) gs = 1e-5;
  return (float)gs;
}

// ---------- abs-mean reduction (fp64 accumulate, 4 weights) ----------
__global__ __launch_bounds__(256) void absmean_kernel(
    const float* __restrict__ w0, const float* __restrict__ w1,
    const float* __restrict__ w2, const float* __restrict__ w3,
    double* __restrict__ sums) {
  const float* w = blockIdx.y == 0 ? w0 : blockIdx.y == 1 ? w1
                 : blockIdx.y == 2 ? w2 : w3;
  double acc = 0.0;
  const int stride = gridDim.x * blockDim.x;
  for (int i = blockIdx.x * blockDim.x + threadIdx.x; i < WELEMS / 4; i += stride) {
    float4 v = ((const float4*)w)[i];
    acc += (double)fabsf(v.x) + (double)fabsf(v.y) +
           (double)fabsf(v.z) + (double)fabsf(v.w);
  }
  acc += __shfl_xor(acc, 1);  acc += __shfl_xor(acc, 2);  acc += __shfl_xor(acc, 4);
  acc += __shfl_xor(acc, 8);  acc += __shfl_xor(acc, 16); acc += __shfl_xor(acc, 32);
  __shared__ double wsum[4];
  const int lane = threadIdx.x & 63, wave = threadIdx.x >> 6;
  if (lane == 0) wsum[wave] = acc;
  __syncthreads();
  if (threadIdx.x == 0)
    atomicAdd(&sums[blockIdx.y], wsum[0] + wsum[1] + wsum[2] + wsum[3]);
}

// ---------- ternary quantize -> bf16 bits ----------
__global__ __launch_bounds__(256) void quant_kernel(
    const float* __restrict__ wsrc, unsigned short* __restrict__ wt,
    const double* __restrict__ sums, int gidx) {
  const float gf = gamma_of(sums, gidx);
  const int i = blockIdx.x * 256 + threadIdx.x;
  float4 v = ((const float4*)wsrc)[i];
  u16x4 r;
  r[0] = f2bf(fminf(1.f, fmaxf(-1.f, rintf(v.x / gf))));
  r[1] = f2bf(fminf(1.f, fmaxf(-1.f, rintf(v.y / gf))));
  r[2] = f2bf(fminf(1.f, fmaxf(-1.f, rintf(v.z / gf))));
  r[3] = f2bf(fminf(1.f, fmaxf(-1.f, rintf(v.w / gf))));
  ((u16x4*)wt)[i] = r;
}

// ---------- f32 -> bf16 convert ----------
__global__ __launch_bounds__(256) void cvt_bf16_kernel(
    const float* __restrict__ x, unsigned short* __restrict__ xb) {
  const int i = blockIdx.x * 256 + threadIdx.x;
  float4 v = ((const float4*)x)[i];
  u16x4 r;
  r[0] = f2bf(v.x); r[1] = f2bf(v.y); r[2] = f2bf(v.z); r[3] = f2bf(v.w);
  ((u16x4*)xb)[i] = r;
}

// ---------- GEMM: 8-phase 256x256 template (m201-derived), BK=64 ----------
// 8 waves (2M x 4N), per-wave output 128x64. LDS 128KB: A[2dbuf][2half][128][128B] at 0,
// B same at 65536. Static buffer offsets (no pointer rotation). Per phase:
// {4 A ds_reads (+8 B at K-tile start); stage 1 half-tile; s_barrier; lgkmcnt(0)+sched;
//  setprio(1); 16 MFMA; setprio(0); [vmcnt(4) at phases 4,8]; s_barrier}.
// Stage targets are freed >=1 barrier earlier; counted vmcnt keeps 2 halves in flight.
// Swizzle (row&7)<<4 on stage-SOURCE and read (2-way conflict = free, rule #21).
// MODE 0: bf16 out (row,col). MODE 1: bf16 transposed to (b,h,d,t). MODE 2: f32 out.
#define NOSTAGE {}
#define WAIT4 { asm volatile("s_waitcnt vmcnt(4)" ::: "memory"); __builtin_amdgcn_sched_barrier(0); }
#define WAIT0 { asm volatile("s_waitcnt vmcnt(0)" ::: "memory"); __builtin_amdgcn_sched_barrier(0); }

#define STAGE_OP(gptr, baseRow, t, h, d, bofs)                                       \
  if ((t) < NT) {                                                                    \
    load_lds16(gptr + (size_t)((baseRow) + (h)*128 + sr) * K + (t)*64 + sce,         \
               smem + (bofs) + (d)*32768 + (h)*16384 + wave*1024);                   \
    load_lds16(gptr + (size_t)((baseRow) + (h)*128 + 64 + sr) * K + (t)*64 + sce,    \
               smem + (bofs) + (d)*32768 + (h)*16384 + 8192 + wave*1024);            \
  }
#define STAGE_A(t, h, d) STAGE_OP(A,  rowBase, t, h, d, 0)
#define STAGE_B(t, h, d) STAGE_OP(Bt, colBase, t, h, d, 65536)

#define PHASE(d, rb, FIRST, STAGES, WAITS)                                            \
  {                                                                                   \
    const char* Ab_ = smem + (d)*32768 + wm*16384;                                    \
    s16x8 af[2][2];                                                                   \
    _Pragma("unroll") for (int j = 0; j < 2; ++j)                                     \
      _Pragma("unroll") for (int kc = 0; kc < 2; ++kc)                                \
        af[j][kc] = *(const s16x8*)(Ab_ + (((rb)+j)*16 + r15)*128                     \
                                    + (((kc<<6) | (g<<4)) ^ swz));                    \
    if (FIRST) {                                                                      \
      const char* Bb_ = smem + 65536 + (d)*32768 + (wn>>1)*16384;                     \
      _Pragma("unroll") for (int fn = 0; fn < 4; ++fn)                                \
        _Pragma("unroll") for (int kc = 0; kc < 2; ++kc)                              \
          bfr[fn*2+kc] = *(const s16x8*)(Bb_ + ((wn&1)*64 + fn*16 + r15)*128          \
                                         + (((kc<<6) | (g<<4)) ^ swz));               \
    }                                                                                 \
    STAGES;                                                                           \
    __builtin_amdgcn_s_barrier();                                                     \
    asm volatile("s_waitcnt lgkmcnt(0)" ::: "memory");                                \
    __builtin_amdgcn_sched_barrier(0);                                                \
    __builtin_amdgcn_s_setprio(1);                                                    \
    _Pragma("unroll") for (int j = 0; j < 2; ++j)                                     \
      _Pragma("unroll") for (int fn = 0; fn < 4; ++fn)                                \
        _Pragma("unroll") for (int kc = 0; kc < 2; ++kc)                              \
          acc[(rb)+j][fn] = __builtin_amdgcn_mfma_f32_16x16x32_bf16(                  \
              af[j][kc], bfr[fn*2+kc], acc[(rb)+j][fn], 0, 0, 0);                     \
    __builtin_amdgcn_s_setprio(0);                                                    \
    WAITS;                                                                            \
    __builtin_amdgcn_s_barrier();                                                     \
  }

template <int MODE>
__global__ __launch_bounds__(512, 2) void gemm_bt_kernel(
    const unsigned short* __restrict__ A,
    const unsigned short* __restrict__ Bt,
    void* __restrict__ out,
    const double* __restrict__ sums, int gidx, float escale) {
  constexpr int K = D_MODEL;
  constexpr int NT = K / 64;                 // 32 K-tiles of 64
  extern __shared__ char smem[];

  const int tid = threadIdx.x, lane = tid & 63, wave = tid >> 6;
  const int g = lane >> 4, r15 = lane & 15;
  const int wm = wave >> 2, wn = wave & 3;   // 2M x 4N wave grid

  const int wgid = (blockIdx.x & 7) * 32 + (blockIdx.x >> 3);   // XCD swizzle (256=8*32)
  const int rowBase = (wgid >> 3) * 256, colBase = (wgid & 7) * 256;

  // staging: thread covers rows sr and 64+sr of each 128-row half; 16B at swizzled col
  const int sr = tid >> 3;
  const int sce = ((((tid & 7) * 16) ^ ((sr & 7) << 4)) >> 1);   // element offset in 64-k span
  const int swz = (r15 & 7) << 4;

  f32x4 acc[8][4] = {};
  s16x8 bfr[8];

  // ---- prologue: B(0), A(0), B(1); allow B(1) outstanding
  STAGE_B(0, 0, 0); STAGE_B(0, 1, 0);
  STAGE_A(0, 0, 0); STAGE_A(0, 1, 0);
  STAGE_B(1, 0, 1); STAGE_B(1, 1, 1);
  asm volatile("s_waitcnt vmcnt(4)" ::: "memory");
  __builtin_amdgcn_sched_barrier(0);
  __builtin_amdgcn_s_barrier();

#pragma unroll 1
  for (int it = 0; it < NT / 2; ++it) {
    const int e = 2 * it;
    const bool pf = (e + 2 < NT);
    PHASE(0, 0, true,  STAGE_A(e+1, 0, 1), NOSTAGE);
    PHASE(0, 2, false, STAGE_A(e+1, 1, 1), NOSTAGE);
    PHASE(0, 4, false, STAGE_B(e+2, 0, 0), NOSTAGE);
    if (pf) { PHASE(0, 6, false, STAGE_B(e+2, 1, 0), WAIT4); }
    else    { PHASE(0, 6, false, NOSTAGE,            WAIT0); }
    PHASE(1, 0, true,  STAGE_A(e+2, 0, 0), NOSTAGE);
    PHASE(1, 2, false, STAGE_A(e+2, 1, 0), NOSTAGE);
    PHASE(1, 4, false, STAGE_B(e+3, 0, 1), NOSTAGE);
    if (pf) { PHASE(1, 6, false, STAGE_B(e+3, 1, 1), WAIT4); }
    else    { PHASE(1, 6, false, NOSTAGE,            NOSTAGE); }
  }

  // ---- epilogue
  const float scale = gamma_of(sums, gidx) * escale;
#pragma unroll
  for (int fr = 0; fr < 8; ++fr) {
    const int row0 = rowBase + wm * 128 + fr * 16 + g * 4;   // C/D: row=(l>>4)*4+j
#pragma unroll
    for (int fn = 0; fn < 4; ++fn) {
      const int col = colBase + wn * 64 + fn * 16 + r15;     // C/D: col=l&15
      if constexpr (MODE == 2) {
        float* op = (float*)out;
#pragma unroll
        for (int j = 0; j < 4; ++j)
          op[(size_t)(row0 + j) * D_MODEL + col] = acc[fr][fn][j] * scale;
      } else if constexpr (MODE == 0) {
        unsigned short* op = (unsigned short*)out;
#pragma unroll
        for (int j = 0; j < 4; ++j)
          op[(size_t)(row0 + j) * D_MODEL + col] = f2bf(acc[fr][fn][j] * scale);
      } else {  // MODE 1: write V^T laid out (b, h, d, t); 4 j's are contiguous t
        unsigned short* op = (unsigned short*)out;
        const int bb = row0 >> 11, tt = row0 & 2047;
        const int hh = col >> 7,  d = col & 127;
        u16x4 r;
#pragma unroll
        for (int j = 0; j < 4; ++j) r[j] = f2bf(acc[fr][fn][j] * scale);
        *(u16x4*)(op + (((size_t)bb * NHEAD + hh) * DHEAD + d) * SEQ + tt) = r;
      }
    }
  }
}

// ---------- causal flash attention (persistent blocks + work-stealing, R9 measured) ----------
__global__ __launch_bounds__(256, 4) void attn_kernel(
    const unsigned short* __restrict__ qg,
    const unsigned short* __restrict__ kg,
    const unsigned short* __restrict__ vtg,
    unsigned short* __restrict__ og,
    int* __restrict__ counter) {
  __shared__ unsigned short Ks[64 * 128];    // [key][d]  256B rows, 16KB
  __shared__ unsigned short Vts[128 * 64];   // [d][kv]   128B rows, 16KB
  __shared__ unsigned short Ps[4][1024];     // per-wave [q16][kv64] 128B rows, 8KB
  __shared__ int s_item;

  const int tid = threadIdx.x, lane = tid & 63, wave = tid >> 6;
  const int g = lane >> 4, r15 = lane & 15;

  char* KsB = (char*)Ks; char* VtsB = (char*)Vts; char* PsB = (char*)(Ps[wave]);

  for (;;) {
    if (tid == 0) s_item = atomicAdd(counter, 1);
    __syncthreads();                         // publish s_item
    const int item = s_item;
    __syncthreads();                         // all read before next overwrite
    if (item >= NITEMS) break;               // block-uniform exit

    const int qs = 31 - (item >> 6);         // heavy strips first (LPT)
    const int bh = item & 63;
    const int b = bh >> 4, h = bh & 15;

    const unsigned short* kbase = kg + (size_t)b * SEQ * D_MODEL + h * DHEAD;
    const unsigned short* vbase = vtg + (size_t)(b * NHEAD + h) * DHEAD * SEQ;

    // Q fragments (A-layout: row=l&15, k=(l>>4)*8), hoisted for the strip
    s16x8 qf[4];
    {
      const unsigned short* qbase =
          qg + (size_t)(b * SEQ + qs * 64 + wave * 16 + r15) * D_MODEL + h * DHEAD;
#pragma unroll
      for (int c = 0; c < 4; ++c) qf[c] = *(const s16x8*)(qbase + c * 32 + g * 8);
    }

    f32x4 oacc[8] = {};
    float mr[4], lr[4];
#pragma unroll
    for (int j = 0; j < 4; ++j) { mr[j] = -1e30f; lr[j] = 0.f; }

    const int nt = qs + 1;                   // KV tiles for this strip

#pragma unroll 1
    for (int t = 0; t < nt; ++t) {
      // ---- stage K (16KB) and Vt (16KB): linear LDS, pre-swizzled global source
#pragma unroll
      for (int rnd = 0; rnd < 4; ++rnd) {
        const int ob = rnd * 4096 + wave * 1024 + lane * 16;
        const int krow = ob >> 8;
        const int ks = (ob & 255) ^ ((krow & 7) << 4);
        load_lds16(kbase + (size_t)(t * 64 + krow) * D_MODEL + (ks >> 1),
                   KsB + rnd * 4096 + wave * 1024);
        const int drow = ob >> 7;
        const int vs = (ob & 127) ^ ((drow & 7) << 4);
        load_lds16(vbase + (size_t)drow * SEQ + t * 64 + (vs >> 1),
                   VtsB + rnd * 4096 + wave * 1024);
      }
      __syncthreads();

      // ---- S = Q K^T  (16 q-rows x 64 keys, log2 units: scale folded into Q)
      f32x4 s[4] = {};
      __builtin_amdgcn_s_setprio(1);
#pragma unroll
      for (int c = 0; c < 4; ++c) {
#pragma unroll
        for (int n = 0; n < 4; ++n) {
          const int key = n * 16 + r15;
          const int baddr = (((key << 8) | (c << 6) | (g << 4))) ^ ((key & 7) << 4);
          s16x8 kf = *(const s16x8*)(KsB + baddr);
          s[n] = __builtin_amdgcn_mfma_f32_16x16x32_bf16(qf[c], kf, s[n], 0, 0, 0);
        }
      }
      __builtin_amdgcn_s_setprio(0);

      if (t == qs) {                         // only the diagonal tile needs the causal mask
        const int q0 = qs * 64 + wave * 16 + g * 4;
        const int k0 = t * 64 + r15;
#pragma unroll
        for (int n = 0; n < 4; ++n)
#pragma unroll
          for (int j = 0; j < 4; ++j)
            if (k0 + n * 16 > q0 + j) s[n][j] = -1e30f;
      }
      float pm[4];
#pragma unroll
      for (int j = 0; j < 4; ++j)
        pm[j] = fmaxf(fmaxf(s[0][j], s[1][j]), fmaxf(s[2][j], s[3][j]));
#pragma unroll
      for (int j = 0; j < 4; ++j) {
        pm[j] = fmaxf(pm[j], __shfl_xor(pm[j], 1));
        pm[j] = fmaxf(pm[j], __shfl_xor(pm[j], 2));
        pm[j] = fmaxf(pm[j], __shfl_xor(pm[j], 4));
        pm[j] = fmaxf(pm[j], __shfl_xor(pm[j], 8));
      }
      // defer-max (T13): skip rescale while max growth < 8 (log2 units, P <= 256)
      bool ok = pm[0] <= mr[0] + 8.f && pm[1] <= mr[1] + 8.f &&
                pm[2] <= mr[2] + 8.f && pm[3] <= mr[3] + 8.f;
      if (!__all(ok)) {
#pragma unroll
        for (int j = 0; j < 4; ++j) {
          const float mn = fmaxf(mr[j], pm[j]);
          const float rf = exp2f(mr[j] - mn);
          mr[j] = mn;
          lr[j] *= rf;
#pragma unroll
          for (int n2 = 0; n2 < 8; ++n2) oacc[n2][j] *= rf;
        }
      }
      // ---- P = exp2(S-m): row-sum + bf16 P into swizzled per-wave LDS
      float psum[4] = {0.f, 0.f, 0.f, 0.f};
#pragma unroll
      for (int n = 0; n < 4; ++n) {
        const int keyl = n * 16 + r15;
#pragma unroll
        for (int j = 0; j < 4; ++j) {
          const float p = exp2f(s[n][j] - mr[j]);
          psum[j] += p;
          const int row = g * 4 + j;
          const int baddr = ((row << 7) | (keyl << 1)) ^ ((row & 7) << 4);
          *(unsigned short*)(PsB + baddr) = f2bf(p);
        }
      }
#pragma unroll
      for (int j = 0; j < 4; ++j) {
        psum[j] += __shfl_xor(psum[j], 1);
        psum[j] += __shfl_xor(psum[j], 2);
        psum[j] += __shfl_xor(psum[j], 4);
        psum[j] += __shfl_xor(psum[j], 8);
        lr[j] += psum[j];
      }
      // ---- O += P V   (A = P from per-wave LDS, B = Vt rows; in-wave order is safe)
      __builtin_amdgcn_s_setprio(1);
#pragma unroll
      for (int c2 = 0; c2 < 2; ++c2) {
        const int baddr_p = (((r15 << 7) | (c2 << 6) | (g << 4))) ^ ((r15 & 7) << 4);
        s16x8 pa = *(const s16x8*)(PsB + baddr_p);
#pragma unroll
        for (int n2 = 0; n2 < 8; ++n2) {
          const int d = n2 * 16 + r15;
          const int baddr_v = (((d << 7) | (c2 << 6) | (g << 4))) ^ ((d & 7) << 4);
          s16x8 vf = *(const s16x8*)(VtsB + baddr_v);
          oacc[n2] = __builtin_amdgcn_mfma_f32_16x16x32_bf16(pa, vf, oacc[n2], 0, 0, 0);
        }
      }
      __builtin_amdgcn_s_setprio(0);
      __syncthreads();   // guard Ks/Vts before next tile's staging
    }

    // ---- normalize + write (b,t,h,d)
    unsigned short* obase =
        og + (size_t)(b * SEQ + qs * 64 + wave * 16 + g * 4) * D_MODEL + h * DHEAD;
    float inv[4];
#pragma unroll
    for (int j = 0; j < 4; ++j) inv[j] = 1.f / lr[j];
#pragma unroll
    for (int n2 = 0; n2 < 8; ++n2) {
      const int d = n2 * 16 + r15;
#pragma unroll
      for (int j = 0; j < 4; ++j)
        obase[(size_t)j * D_MODEL + d] = f2bf(oacc[n2][j] * inv[j]);
    }
  }
}

// ---------- launch ----------
extern "C" void kernel_launch(void* const* d_in, const int* in_sizes, int n_in,
                              void* d_out, int out_size, void* d_ws, size_t ws_size,
                              hipStream_t stream) {
  const float* x  = (const float*)d_in[0];
  const float* wq = (const float*)d_in[1];
  const float* wk = (const float*)d_in[2];
  const float* wv = (const float*)d_in[3];
  const float* wo = (const float*)d_in[4];
  float* out = (float*)d_out;

  char* ws = (char*)d_ws;
  double* sums = (double*)ws;                 // 4 doubles at ws+0
  int* cnt = (int*)(ws + 64);                 // work-stealing counter at ws+64
  size_t off = 256;
  unsigned short* wtern = (unsigned short*)(ws + off); off += (size_t)WELEMS * 2;
  unsigned short* xbf   = (unsigned short*)(ws + off); off += (size_t)MROWS * D_MODEL * 2;
  unsigned short* qb    = (unsigned short*)(ws + off); off += (size_t)MROWS * D_MODEL * 2;
  unsigned short* kb    = (unsigned short*)(ws + off); off += (size_t)MROWS * D_MODEL * 2;
  unsigned short* vtb   = (unsigned short*)(ws + off); off += (size_t)MROWS * D_MODEL * 2;
  unsigned short* attn_out = xbf;  // x no longer needed after the 3 QKV GEMMs

  hipMemsetAsync(ws, 0, 256, stream);         // zeroes sums + counter
  absmean_kernel<<<dim3(256, 4), 256, 0, stream>>>(wq, wk, wv, wo, sums);
  cvt_bf16_kernel<<<MROWS * D_MODEL / 4 / 256, 256, 0, stream>>>(x, xbf);

  // Q carries 1/sqrt(128) * log2(e) so attention scores are in log2 units (exp2f native)
  const float qfold = 0.08838834764831845f * 1.4426950408889634f;

  const int ggrid = (MROWS / 256) * (D_MODEL / 256);   // 256 blocks, 1/CU
  const int glds = 131072;                             // 2dbuf x 2half x (A+B)
  quant_kernel<<<WELEMS / 4 / 256, 256, 0, stream>>>(wq, wtern, sums, 0);
  gemm_bt_kernel<0><<<ggrid, 512, glds, stream>>>(xbf, wtern, qb, sums, 0, qfold);
  quant_kernel<<<WELEMS / 4 / 256, 256, 0, stream>>>(wk, wtern, sums, 1);
  gemm_bt_kernel<0><<<ggrid, 512, glds, stream>>>(xbf, wtern, kb, sums, 1, 1.0f);
  quant_kernel<<<WELEMS / 4 / 256, 256, 0, stream>>>(wv, wtern, sums, 2);
  gemm_bt_kernel<1><<<ggrid, 512, glds, stream>>>(xbf, wtern, vtb, sums, 2, 1.0f);

  attn_kernel<<<dim3(1024), 256, 0, stream>>>(qb, kb, vtb, attn_out, cnt);

  quant_kernel<<<WELEMS / 4 / 256, 256, 0, stream>>>(wo, wtern, sums, 3);
  gemm_bt_kernel<2><<<ggrid, 512, glds, stream>>>(attn_out, wtern, out, sums, 3, 1.0f);
}